// Round 8
// baseline (1258.137 us; speedup 1.0000x reference)
//
#include <hip/hip_runtime.h>
#include <math.h>

#define B_ 8
#define N_ 4096
#define PL_ (8 * 4096 * 32)   // elements per bf16 plane (knn feature planes)

// ---------------------------------------------------------------- bf16 split helpers
__device__ __forceinline__ unsigned short bf16rne(float x) {
    unsigned int u = __float_as_uint(x);
    return (unsigned short)((u + 0x7FFFu + ((u >> 16) & 1u)) >> 16);
}
__device__ __forceinline__ float bff(unsigned short h) {
    return __uint_as_float((unsigned int)h << 16);
}
__device__ __forceinline__ void cvt_hl(unsigned short* base, int numel, int idx, float x) {
    unsigned short h = bf16rne(x);
    base[idx] = h;
    base[numel + idx] = bf16rne(x - bff(h));
}

typedef __attribute__((ext_vector_type(8))) short bf16x8;
typedef __attribute__((ext_vector_type(4))) float f32x4;

#define MF16(a, b, c) __builtin_amdgcn_mfma_f32_16x16x32_bf16((a), (b), (c), 0, 0, 0)

// ---------------------------------------------------------------- unified prep kernel
__global__ __launch_bounds__(256) void prep_kernel(
    const float* __restrict__ w0, const float* __restrict__ w1,
    const float* __restrict__ w2, const float* __restrict__ w3,
    const float* __restrict__ w4, const float* __restrict__ w5,
    const float* __restrict__ w6, const float* __restrict__ w8,
    const float* __restrict__ w9, const float* __restrict__ w10,
    const float* __restrict__ w11, const float* __restrict__ w12,
    const float* __restrict__ w13, const float* __restrict__ w14,
    const float* __restrict__ wf1, const float* __restrict__ bf1,
    const float* __restrict__ xyz,
    float* __restrict__ wt, float* __restrict__ gbuf, float* __restrict__ sqbuf,
    unsigned short* __restrict__ xyzp) {
    const int g = blockIdx.x * 256 + threadIdx.x;
    unsigned short* wus = (unsigned short*)(wt + 3840);

    if (g < 3584) {                              // e1 weights (fp32, [i][o])
        if (g < 320)       { int i = g >> 5, o = g & 31;             wt[g] = w0[o * 10 + i]; }
        else if (g < 1344) { int l = g - 320;  int i = l >> 5, o = l & 31; wt[g] = w1[o * 32 + i]; }
        else if (g < 1536) { int l = g - 1344; int i = l >> 5, o = l & 31; wt[g] = w2[o * 6 + i]; }
        else if (g < 2560) { int l = g - 1536; int i = l >> 5, o = l & 31; wt[g] = w3[o * 32 + i]; }
        else               { int l = g - 2560; int i = l >> 5, o = l & 31; wt[g] = w4[o * 32 + i]; }
    }
    else if (g < 3840)   { int l = g - 3584; wt[g] = (l < 128) ? bf1[l] : 0.0f; }                      // bpre
    else if (g < 12032)  { int l = g - 3840; int o = l >> 5, i = l & 31;                               // wpre 256x32
                           float x = (o < 128) ? wf1[o * 64 + i] : wf1[(o - 128) * 64 + 32 + i];
                           cvt_hl(wus + 0, 8192, l, x); }
    else if (g < 28416)  { int l = g - 12032;  cvt_hl(wus + 16384, 16384, l, w10[l]); }                // wc1 128x128
    else if (g < 159488) { int l = g - 28416;  cvt_hl(wus + 49152, 131072, l, w11[l]); }               // wc2 1024x128
    else if (g < 241408) { int l = g - 159488; int o = l / 160, i = l - o * 160;                       // wc3 512x160
                           cvt_hl(wus + 311296, 81920, l, w12[o * 1184 + i]); }
    else if (g < 372480) { int l = g - 241408; cvt_hl(wus + 475136, 131072, l, w13[l]); }              // wc4 256x512
    else if (g < 405248) { int l = g - 372480; cvt_hl(wus + 737280, 32768, l, w14[l]); }               // wc5 128x256
    else if (g < 409344) { int l = g - 405248; int o = l >> 5, k = l & 31;                             // wg1p 128x32 pad
                           float x = (k < 10) ? w5[o * 10 + k] : 0.0f;
                           cvt_hl(wus + 802816, 4096, l, x); }
    else if (g < 425728) { int l = g - 409344; cvt_hl(wus + 811008, 16384, l, w6[l]); }                // wg2p 128x128
    else if (g < 442112) { int l = g - 425728; cvt_hl(wus + 843776, 16384, l, w8[l]); }                // wf2p
    else if (g < 458496) { int l = g - 442112; cvt_hl(wus + 876544, 16384, l, w9[l]); }                // wf3p
    else if (g < 466688) { gbuf[g - 458496] = 0.0f; }
    else if (g < 499456) { int l = g - 466688;
                           const float* p = xyz + (size_t)l * 3;
                           sqbuf[l] = fmaf(p[0], p[0], fmaf(p[1], p[1], p[2] * p[2])); }
    else if (g < 532224) {                       // xyz h/m/l planes, K=32 zero-padded
        int row = g - 499456;
        const float* p = xyz + (size_t)row * 3;
        unsigned short hv[8] = {0,0,0,0,0,0,0,0};
        unsigned short mv[8] = {0,0,0,0,0,0,0,0};
        unsigned short lv[8] = {0,0,0,0,0,0,0,0};
        #pragma unroll
        for (int c = 0; c < 3; ++c) {
            float v = p[c];
            unsigned short h = bf16rne(v); float d = v - bff(h);
            unsigned short m = bf16rne(d);
            hv[c] = h; mv[c] = m; lv[c] = bf16rne(d - bff(m));
        }
        uint4 z = make_uint4(0u, 0u, 0u, 0u);
        unsigned short* d0 = xyzp + (size_t)row * 32;
        unsigned short* d1 = d0 + PL_;
        unsigned short* d2 = d0 + 2 * PL_;
        *(uint4*)d0 = *(uint4*)hv; *(uint4*)(d0 + 8) = z; *(uint4*)(d0 + 16) = z; *(uint4*)(d0 + 24) = z;
        *(uint4*)d1 = *(uint4*)mv; *(uint4*)(d1 + 8) = z; *(uint4*)(d1 + 16) = z; *(uint4*)(d1 + 24) = z;
        *(uint4*)d2 = *(uint4*)lv; *(uint4*)(d2 + 8) = z; *(uint4*)(d2 + 16) = z; *(uint4*)(d2 + 24) = z;
    }
}

// ---------------------------------------------------------------- fea1 -> h/m/l planes + sq (fused)
__global__ __launch_bounds__(256) void fea1p_kernel(
    const float* __restrict__ F, unsigned short* __restrict__ P, float* __restrict__ SQ) {
    int row = blockIdx.x * 256 + threadIdx.x;    // 32768 rows
    const float* x = F + (size_t)row * 32;
    float s = 0.0f;
    unsigned short hb[32], mb[32], lb[32];
    #pragma unroll
    for (int c = 0; c < 32; ++c) {
        float v = x[c];
        s = fmaf(v, v, s);
        unsigned short h = bf16rne(v); float d = v - bff(h);
        unsigned short m = bf16rne(d);
        hb[c] = h; mb[c] = m; lb[c] = bf16rne(d - bff(m));
    }
    SQ[row] = s;
    unsigned short* d0 = P + (size_t)row * 32;
    #pragma unroll
    for (int q = 0; q < 4; ++q) {
        *(uint4*)(d0 + 8 * q)           = *(uint4*)&hb[8 * q];
        *(uint4*)(d0 + PL_ + 8 * q)     = *(uint4*)&mb[8 * q];
        *(uint4*)(d0 + 2 * PL_ + 8 * q) = *(uint4*)&lb[8 * q];
    }
}

// ---------------------------------------------------------------- knn (top-16, MFMA two-pass)

__device__ __forceinline__ void cas_asc(unsigned long long& x, unsigned long long& y) {
    unsigned long long a = x, b = y;
    bool sw = a > b;
    x = sw ? b : a;
    y = sw ? a : b;
}

__device__ __forceinline__ void merge_top(unsigned long long (&k)[16],
                                          const unsigned long long (&o)[16]) {
    #pragma unroll
    for (int i = 0; i < 16; ++i) {
        unsigned long long bb = o[15 - i];
        if (bb > k[i]) k[i] = bb;
    }
    #pragma unroll
    for (int st = 8; st >= 1; st >>= 1)
        #pragma unroll
        for (int i = 0; i < 16; ++i)
            if ((i & st) == 0) cas_asc(k[i], k[i + st]);
}

__device__ __forceinline__ void casv(float& x, float& y) {
    float lo = fminf(x, y), hi = fmaxf(x, y);
    x = lo; y = hi;
}

__device__ __forceinline__ void sortv16(float (&v)[16]) {   // ascending
    #pragma unroll
    for (int sz = 2; sz <= 16; sz <<= 1)
        #pragma unroll
        for (int st = sz >> 1; st >= 1; st >>= 1)
            #pragma unroll
            for (int i = 0; i < 16; ++i)
                if ((i & st) == 0) {
                    if ((i & sz) == 0) casv(v[i], v[i + st]);
                    else                casv(v[i + st], v[i]);
                }
}

__device__ __forceinline__ void mergev(float (&kv)[16], const float (&nv)[16]) {
    #pragma unroll
    for (int i = 0; i < 16; ++i) kv[i] = fmaxf(kv[i], nv[15 - i]);
    #pragma unroll
    for (int st = 8; st >= 1; st >>= 1)
        #pragma unroll
        for (int i = 0; i < 16; ++i)
            if ((i & st) == 0) casv(kv[i], kv[i + st]);
}

__global__ __launch_bounds__(256, 4) void knn_kernel(
    const unsigned short* __restrict__ P, const float* __restrict__ SQ,
    unsigned long long* __restrict__ Kout) {
    __shared__ __align__(16) unsigned short Bs[3][64][40];   // 15360 B
    __shared__ __align__(16) char U[17408];                  // Ds (pass1, per-wave) | cap (pass2)
    __shared__ float tau_sm[64];
    __shared__ int cnt[64];
    const int t = threadIdx.x;
    const int b = blockIdx.y;
    const int r0 = blockIdx.x * 64;
    const int half = blockIdx.z;
    const int H0 = half * 2048;
    const int lane = t & 63, w = t >> 6;
    const int lr = lane & 15, lg = lane >> 4;
    const int kb = lg << 3;
    const int sc = t >> 2, sq8 = (t & 3) << 3;               // staging: col, ch-offset

    float* Ds = (float*)U + w * 1088;                        // [16][68] per wave
    unsigned long long* cap = (unsigned long long*)U;        // [64][32] (pass2 overlay)

    const unsigned short* ap = P + ((size_t)(b * N_) + r0 + 16 * w + lr) * 32 + kb;
    const bf16x8 ah = *(const bf16x8*)ap;
    const bf16x8 am = *(const bf16x8*)(ap + PL_);
    const bf16x8 al = *(const bf16x8*)(ap + 2 * PL_);
    const f32x4 sqr4 = *(const f32x4*)&SQ[(size_t)b * N_ + r0 + 16 * w + 4 * lg];

    const float* SQc = SQ + (size_t)b * N_ + H0;
    const unsigned short* Pc = P + ((size_t)(b * N_) + H0) * 32;

    uint4 sgh, sgm, sgl;                                     // staging registers
    auto issue = [&](int tt) {
        const unsigned short* src = Pc + (size_t)(tt * 64 + sc) * 32 + sq8;
        sgh = *(const uint4*)src;
        sgm = *(const uint4*)(src + PL_);
        sgl = *(const uint4*)(src + 2 * PL_);
    };
    auto commit = [&]() {
        *(uint4*)&Bs[0][sc][sq8] = sgh;
        *(uint4*)&Bs[1][sc][sq8] = sgm;
        *(uint4*)&Bs[2][sc][sq8] = sgl;
    };

    float kv[16];
    #pragma unroll
    for (int j = 0; j < 16; ++j) kv[j] = -3.4e38f;

    issue(0);
    // ---- pass 1 ----
    for (int tt = 0; tt < 32; ++tt) {
        commit();
        __syncthreads();                                     // Bs ready
        if (tt + 1 < 32) issue(tt + 1);                      // latency hides under compute
        #pragma unroll
        for (int j = 0; j < 4; ++j) {
            int cc = 16 * j + lr;
            bf16x8 bh = *(const bf16x8*)&Bs[0][cc][kb];
            bf16x8 bm = *(const bf16x8*)&Bs[1][cc][kb];
            bf16x8 bl = *(const bf16x8*)&Bs[2][cc][kb];
            f32x4 a = {0.0f, 0.0f, 0.0f, 0.0f};
            a = MF16(ah, bh, a); a = MF16(am, bh, a); a = MF16(ah, bm, a);
            a = MF16(am, bm, a); a = MF16(al, bh, a); a = MF16(ah, bl, a);
            float sqcv = SQc[tt * 64 + cc];
            #pragma unroll
            for (int r = 0; r < 4; ++r)
                Ds[(4 * lg + r) * 68 + cc] = fmaf(2.0f, a[r], -sqr4[r]) - sqcv;
        }
        float nv[16];
        #pragma unroll
        for (int q = 0; q < 4; ++q)
            *(float4*)&nv[4 * q] = *(const float4*)&Ds[lr * 68 + lg * 16 + 4 * q];
        sortv16(nv);
        mergev(kv, nv);
        __syncthreads();                                     // Bs reads done
    }
    issue(0);                                                // pass-2 tile 0 prefetch

    // ---- tau: merge 4 quarters across lanes (shfl), 16th value per row ----
    #pragma unroll
    for (int st = 16; st <= 32; st <<= 1) {
        float ov[16];
        #pragma unroll
        for (int i = 0; i < 16; ++i) ov[i] = __shfl_xor(kv[15 - i], st);
        #pragma unroll
        for (int i = 0; i < 16; ++i) kv[i] = fmaxf(kv[i], ov[i]);
        #pragma unroll
        for (int s2 = 8; s2 >= 1; s2 >>= 1)
            #pragma unroll
            for (int i = 0; i < 16; ++i)
                if ((i & s2) == 0) casv(kv[i], kv[i + s2]);
    }
    if (lane < 16) { tau_sm[w * 16 + lane] = kv[0]; cnt[w * 16 + lane] = 0; }
    const f32x4 taur4 = *(const f32x4*)&tau_sm[w * 16 + 4 * lg];

    // ---- pass 2: recompute, compact e >= tau ----
    for (int tt = 0; tt < 32; ++tt) {
        commit();
        __syncthreads();                                     // also guards Ds->cap overlay
        if (tt + 1 < 32) issue(tt + 1);
        #pragma unroll
        for (int j = 0; j < 4; ++j) {
            int cc = 16 * j + lr;
            bf16x8 bh = *(const bf16x8*)&Bs[0][cc][kb];
            bf16x8 bm = *(const bf16x8*)&Bs[1][cc][kb];
            bf16x8 bl = *(const bf16x8*)&Bs[2][cc][kb];
            f32x4 a = {0.0f, 0.0f, 0.0f, 0.0f};
            a = MF16(ah, bh, a); a = MF16(am, bh, a); a = MF16(ah, bm, a);
            a = MF16(am, bm, a); a = MF16(al, bh, a); a = MF16(ah, bl, a);
            float sqcv = SQc[tt * 64 + cc];
            #pragma unroll
            for (int r = 0; r < 4; ++r) {
                float e = fmaf(2.0f, a[r], -sqr4[r]) - sqcv;
                if (e >= taur4[r]) {
                    int row = 16 * w + 4 * lg + r;
                    unsigned int u = __float_as_uint(e);
                    unsigned int ou = (u & 0x80000000u) ? ~u : (u | 0x80000000u);
                    unsigned long long key = ((unsigned long long)ou << 32)
                                           | (unsigned int)(4095 - (H0 + tt * 64 + cc));
                    int pos = atomicAdd(&cnt[row], 1);
                    if (pos < 32) cap[row * 32 + pos] = key;
                }
            }
        }
        __syncthreads();
    }

    // ---- final per-row exact top-16 (u64 keys, asc) ----
    if (t < 64) {
        int n = min(cnt[t], 32);
        unsigned long long K[16];
        #pragma unroll
        for (int j = 0; j < 16; ++j) K[j] = 0ull;
        for (int i = 0; i < n; ++i) {
            unsigned long long v = cap[t * 32 + i];
            if (v > K[0]) {
                K[0] = v;
                #pragma unroll
                for (int s = 0; s < 15; ++s) cas_asc(K[s], K[s + 1]);
            }
        }
        size_t obase = (((size_t)b * 2 + half) * N_ + r0 + t) * 16;
        #pragma unroll
        for (int j = 0; j < 16; ++j) Kout[obase + j] = K[j];
    }
}

__global__ __launch_bounds__(256) void knn_merge_kernel(
    const unsigned long long* __restrict__ Kbuf, int* __restrict__ IDX) {
    int gid = blockIdx.x * 256 + threadIdx.x;
    int b = gid >> 12, r = gid & 4095;
    unsigned long long K0[16], K1[16];
    const unsigned long long* p0 = Kbuf + (((size_t)b * 2 + 0) * N_ + r) * 16;
    const unsigned long long* p1 = Kbuf + (((size_t)b * 2 + 1) * N_ + r) * 16;
    #pragma unroll
    for (int j = 0; j < 16; ++j) { K0[j] = p0[j]; K1[j] = p1[j]; }
    merge_top(K0, K1);
    size_t ob = ((size_t)b * N_ + r) * 16;
    #pragma unroll
    for (int j = 0; j < 16; ++j)
        IDX[ob + j] = 4095 - (int)(unsigned int)(K0[15 - j] & 0xFFFFFFFFu);
}

// ---------------------------------------------------------------- edgeconv 1 (xyz, C=3 -> 32)

__global__ __launch_bounds__(256, 4) void e1_kernel(
    const float* __restrict__ xyz, const int* __restrict__ idx1,
    const float* __restrict__ wte1,
    const float* __restrict__ bg1, const float* __restrict__ bg2,
    const float* __restrict__ bf1, const float* __restrict__ bf2,
    const float* __restrict__ bf3,
    float* __restrict__ fea1) {
    __shared__ __align__(16) float Ain[10 * 132];
    __shared__ __align__(16) float Bu0[32 * 132];
    __shared__ __align__(16) float Bu1[32 * 132];
    __shared__ __align__(16) float wl[3584];
    __shared__ float bl[5][32];
    __shared__ __align__(16) float Pm1[4][8][32];
    __shared__ int idxl[128];
    const int t = threadIdx.x;
    const int b = blockIdx.x >> 9;
    const int n0 = (blockIdx.x & 511) << 3;
    const int et = (t & 31) << 2;
    const int ct = (t >> 5) << 2;

    for (int i = t; i < 3584; i += 256) wl[i] = wte1[i];
    if (t < 32) {
        bl[0][t] = bg1[t]; bl[1][t] = bg2[t]; bl[2][t] = bf1[t];
        bl[3][t] = bf2[t]; bl[4][t] = bf3[t];
    }
    if (t < 128) idxl[t] = idx1[((size_t)b * N_ + n0 + (t >> 4)) * 16 + (t & 15)];
    __syncthreads();
    if (t < 128) {
        int p = t >> 4, n = n0 + p, m = idxl[t];
        const float* xc = xyz + ((size_t)b * N_ + n) * 3;
        const float* xk = xyz + ((size_t)b * N_ + m) * 3;
        float c0 = xc[0], c1v = xc[1], c2v = xc[2];
        float k0 = xk[0], k1 = xk[1], k2 = xk[2];
        float r0 = c0 - k0, r1 = c1v - k1, r2 = c2v - k2;
        Ain[0 * 132 + t] = sqrtf(r0 * r0 + r1 * r1 + r2 * r2);
        Ain[1 * 132 + t] = c0;  Ain[2 * 132 + t] = c1v; Ain[3 * 132 + t] = c2v;
        Ain[4 * 132 + t] = k0;  Ain[5 * 132 + t] = k1;  Ain[6 * 132 + t] = k2;
        Ain[7 * 132 + t] = r0;  Ain[8 * 132 + t] = r1;  Ain[9 * 132 + t] = r2;
    }
    __syncthreads();

    float acc[4][4];
    auto gem = [&](int KK, const float* Asrc, int woff) {
        #pragma unroll
        for (int ii = 0; ii < 4; ++ii)
            #pragma unroll
            for (int jj = 0; jj < 4; ++jj) acc[ii][jj] = 0.0f;
        for (int i = 0; i < KK; ++i) {
            float a4[4], w4[4];
            *(float4*)a4 = *(const float4*)&Asrc[i * 132 + et];
            *(float4*)w4 = *(const float4*)&wl[woff + i * 32 + ct];
            #pragma unroll
            for (int ii = 0; ii < 4; ++ii)
                #pragma unroll
                for (int jj = 0; jj < 4; ++jj)
                    acc[ii][jj] = fmaf(a4[ii], w4[jj], acc[ii][jj]);
        }
    };
    auto wrout = [&](float* dst, const float* brow) {
        #pragma unroll
        for (int jj = 0; jj < 4; ++jj) {
            float tmp[4];
            #pragma unroll
            for (int ii = 0; ii < 4; ++ii) tmp[ii] = fmaxf(acc[ii][jj] + brow[ct + jj], 0.0f);
            *(float4*)&dst[(ct + jj) * 132 + et] = *(float4*)tmp;
        }
    };

    gem(10, Ain, 0);          wrout(Bu1, bl[0]);   __syncthreads();
    gem(32, Bu1, 320);
    float g2r[4][4];
    #pragma unroll
    for (int ii = 0; ii < 4; ++ii)
        #pragma unroll
        for (int jj = 0; jj < 4; ++jj)
            g2r[ii][jj] = fmaxf(acc[ii][jj] + bl[1][ct + jj], 0.0f);
    gem(6, Ain + 132, 1344);  wrout(Bu0, bl[2]);   __syncthreads();
    gem(32, Bu0, 1536);       wrout(Bu1, bl[3]);   __syncthreads();
    gem(32, Bu1, 2560);

    float pm[4];
    #pragma unroll
    for (int jj = 0; jj < 4; ++jj) {
        float mx = 0.0f;
        #pragma unroll
        for (int ii = 0; ii < 4; ++ii) {
            float f3 = fmaxf(acc[ii][jj] + bl[4][ct + jj], 0.0f);
            mx = fmaxf(mx, g2r[ii][jj] * f3);
        }
        pm[jj] = mx;
    }
    const int sub = t & 3, pl = (t & 31) >> 2;
    *(float4*)&Pm1[sub][pl][ct] = *(float4*)pm;
    __syncthreads();
    {
        int p = t >> 5, c = t & 31;
        float v = fmaxf(fmaxf(Pm1[0][p][c], Pm1[1][p][c]), fmaxf(Pm1[2][p][c], Pm1[3][p][c]));
        fea1[((size_t)b * N_ + n0 + p) * 32 + c] = v;
    }
}

// ---------------------------------------------------------------- edgeconv 2 (split-bf16 MFMA, 4-point tile)
// 4 points / 64 edges per block, 256 threads, 4 waves (2x2 over o-half x e-half),
// LDS ~34.5KB -> 4 blocks/CU (2x the 8-pt tile's TLP). Per-output MFMA sequence
// identical to the 8-pt version -> bit-identical results.

__global__ __launch_bounds__(256, 2) void e2_kernel(
    const float* __restrict__ xyz, const int* __restrict__ idx2,
    const float* __restrict__ CfPf,
    const unsigned short* __restrict__ wg1p, const unsigned short* __restrict__ wg2p,
    const unsigned short* __restrict__ wf2p, const unsigned short* __restrict__ wf3p,
    const float* __restrict__ bg1, const float* __restrict__ bg2,
    const float* __restrict__ bf2, const float* __restrict__ bf3,
    float* __restrict__ fea2) {
    __shared__ __align__(16) unsigned short Ah[64 * 128];    // 16KB hi plane [e][ch]
    __shared__ __align__(16) unsigned short Al[64 * 128];    // 16KB lo plane
    __shared__ float bb[4][128];
    __shared__ int idxl[64];
    const int t = threadIdx.x;
    const int b = blockIdx.x >> 10;
    const int n0 = (blockIdx.x & 1023) << 2;
    const int lane = t & 63, w = t >> 6;
    const int wr = (w >> 1) << 6;    // o half: 0 / 64
    const int wc = (w & 1) << 5;     // e half: 0 / 32
    const int lr = lane & 15, lg = lane >> 4;
    const int kb = lg << 3;

    auto swz = [](int e, int bo) { return e * 256 + (bo ^ ((e & 7) << 4)); };

    for (int i = t; i < 512; i += 256) {
        const float* bp = (i < 128) ? bg1 : (i < 256) ? bg2 : (i < 384) ? bf2 : bf3;
        bb[i >> 7][i & 127] = bp[i & 127];
    }
    if (t < 64) idxl[t] = idx2[((size_t)b * N_ + n0 + (t >> 4)) * 16 + (t & 15)];
    __syncthreads();

    f32x4 acc[4][2];
    const f32x4 zz = {0.0f, 0.0f, 0.0f, 0.0f};
    auto zacc = [&]() {
        #pragma unroll
        for (int i = 0; i < 4; ++i)
            #pragma unroll
            for (int j = 0; j < 2; ++j) acc[i][j] = zz;
    };

    {   // ---- g1: geometry B-fragments in registers, K=32 (10 real + 22 zero) ----
        bf16x8 gbh[2], gbl[2];
        #pragma unroll
        for (int j = 0; j < 2; ++j) {
            float gv[8];
            #pragma unroll
            for (int q = 0; q < 8; ++q) gv[q] = 0.0f;
            if (lg < 2) {
                int e = wc + j * 16 + lr;
                int p = e >> 4, m = idxl[e];
                const float* xc = xyz + ((size_t)b * N_ + n0 + p) * 3;
                const float* xk = xyz + ((size_t)b * N_ + m) * 3;
                float c0 = xc[0], c1 = xc[1], c2 = xc[2];
                float k0 = xk[0], k1 = xk[1], k2 = xk[2];
                float r0 = c0 - k0, r1 = c1 - k1, r2 = c2 - k2;
                if (lg == 0) {
                    gv[0] = sqrtf(r0 * r0 + r1 * r1 + r2 * r2);
                    gv[1] = c0; gv[2] = c1; gv[3] = c2;
                    gv[4] = k0; gv[5] = k1; gv[6] = k2; gv[7] = r0;
                } else { gv[0] = r1; gv[1] = r2; }
            }
            bf16x8 vh, vl;
            #pragma unroll
            for (int q = 0; q < 8; ++q) {
                unsigned short h = bf16rne(gv[q]);
                vh[q] = (short)h;
                vl[q] = (short)bf16rne(gv[q] - bff(h));
            }
            gbh[j] = vh; gbl[j] = vl;
        }
        zacc();
        #pragma unroll
        for (int i = 0; i < 4; ++i) {
            size_t off = (size_t)(wr + i * 16 + lr) * 32 + kb;
            bf16x8 wh = *(const bf16x8*)(wg1p + off);
            bf16x8 wl_ = *(const bf16x8*)(wg1p + 4096 + off);
            #pragma unroll
            for (int j = 0; j < 2; ++j) {
                acc[i][j] = MF16(wh, gbh[j], acc[i][j]);
                acc[i][j] = MF16(wl_, gbh[j], acc[i][j]);
                acc[i][j] = MF16(wh, gbl[j], acc[i][j]);
            }
        }
    }

    auto epi_store = [&](const float* brow) {
        #pragma unroll
        for (int i = 0; i < 4; ++i) {
            int o4 = wr + i * 16 + lg * 4;
            float bv[4];
            *(float4*)bv = *(const float4*)&brow[o4];
            #pragma unroll
            for (int j = 0; j < 2; ++j) {
                int e = wc + j * 16 + lr;
                unsigned short h[4], l[4];
                #pragma unroll
                for (int r = 0; r < 4; ++r) {
                    float v = fmaxf(acc[i][j][r] + bv[r], 0.0f);
                    h[r] = bf16rne(v);
                    l[r] = bf16rne(v - bff(h[r]));
                }
                int bo = swz(e, o4 * 2);
                *(ushort4*)((char*)Ah + bo) = make_ushort4(h[0], h[1], h[2], h[3]);
                *(ushort4*)((char*)Al + bo) = make_ushort4(l[0], l[1], l[2], l[3]);
            }
        }
    };
    epi_store(bb[0]);
    __syncthreads();

    // K=128 GEMM: W from global ([o][128] hi/lo), activations from swizzled LDS planes
    auto gemmK = [&](const unsigned short* __restrict__ Wp) {
        zacc();
        #pragma unroll
        for (int ks = 0; ks < 4; ++ks) {
            bf16x8 xh[2], xl[2];
            #pragma unroll
            for (int j = 0; j < 2; ++j) {
                int e = wc + j * 16 + lr;
                int bo = swz(e, (ks * 32 + kb) * 2);
                xh[j] = *(const bf16x8*)((const char*)Ah + bo);
                xl[j] = *(const bf16x8*)((const char*)Al + bo);
            }
            #pragma unroll
            for (int i = 0; i < 4; ++i) {
                size_t off = (size_t)(wr + i * 16 + lr) * 128 + ks * 32 + kb;
                bf16x8 wh = *(const bf16x8*)(Wp + off);
                bf16x8 wl_ = *(const bf16x8*)(Wp + 16384 + off);
                #pragma unroll
                for (int j = 0; j < 2; ++j) {
                    acc[i][j] = MF16(wh, xh[j], acc[i][j]);
                    acc[i][j] = MF16(wl_, xh[j], acc[i][j]);
                    acc[i][j] = MF16(wh, xl[j], acc[i][j]);
                }
            }
        }
    };

    gemmK(wg2p);
    float g2r[4][2][4];
    #pragma unroll
    for (int i = 0; i < 4; ++i) {
        float bv[4];
        *(float4*)bv = *(const float4*)&bb[1][wr + i * 16 + lg * 4];
        #pragma unroll
        for (int j = 0; j < 2; ++j)
            #pragma unroll
            for (int r = 0; r < 4; ++r)
                g2r[i][j][r] = fmaxf(acc[i][j][r] + bv[r], 0.0f);
    }
    __syncthreads();

    {   // ---- f1: gather relu(Cf[n] + Pf[m]) -> planes (64 e x 128 ch) ----
        int e = t & 63, hf = t >> 6;                         // hf 0..3, 32 ch each
        int n = n0 + (e >> 4), m = idxl[e];
        const float* crow = CfPf + ((size_t)b * N_ + n) * 256 + hf * 32;
        const float* prow = CfPf + ((size_t)b * N_ + m) * 256 + 128 + hf * 32;
        #pragma unroll
        for (int q = 0; q < 8; ++q) {
            float4 cc = *(const float4*)(crow + q * 4);
            float4 pp = *(const float4*)(prow + q * 4);
            float v[4] = { fmaxf(cc.x + pp.x, 0.0f), fmaxf(cc.y + pp.y, 0.0f),
                           fmaxf(cc.z + pp.z, 0.0f), fmaxf(cc.w + pp.w, 0.0f) };
            unsigned short h[4], l[4];
            #pragma unroll
            for (int r = 0; r < 4; ++r) {
                h[r] = bf16rne(v[r]);
                l[r] = bf16rne(v[r] - bff(h[r]));
            }
            int bo = swz(e, (hf * 32 + q * 4) * 2);
            *(ushort4*)((char*)Ah + bo) = make_ushort4(h[0], h[1], h[2], h[3]);
            *(ushort4*)((char*)Al + bo) = make_ushort4(l[0], l[1], l[2], l[3]);
        }
    }
    __syncthreads();

    gemmK(wf2p);
    __syncthreads();
    epi_store(bb[2]);
    __syncthreads();

    gemmK(wf3p);
    #pragma unroll
    for (int j = 0; j < 2; ++j) {
        int p = (wc >> 4) + j;           // point within block (0..3)
        #pragma unroll
        for (int i = 0; i < 4; ++i) {
            int o4 = wr + i * 16 + lg * 4;
            float bv[4];
            *(float4*)bv = *(const float4*)&bb[3][o4];
            float vr[4];
            #pragma unroll
            for (int r = 0; r < 4; ++r) {
                float f3v = fmaxf(acc[i][j][r] + bv[r], 0.0f);
                float v = g2r[i][j][r] * f3v;
                v = fmaxf(v, __shfl_xor(v, 1));
                v = fmaxf(v, __shfl_xor(v, 2));
                v = fmaxf(v, __shfl_xor(v, 4));
                v = fmaxf(v, __shfl_xor(v, 8));
                vr[r] = v;
            }
            if (lr == 0)
                *(float4*)(fea2 + ((size_t)b * N_ + n0 + p) * 128 + o4) = *(float4*)vr;
        }
    }
}

// ---------------------------------------------------------------- split-bf16 MFMA pointwise GEMM (head)

template<int RELU, int BMODE, int GMAX>
__global__ __launch_bounds__(256) void gemm_mfma(
    const float* __restrict__ X1, int S1, int K1,
    const float* __restrict__ X2, int S2, int Ktot,
    const unsigned short* __restrict__ Wc, const float* __restrict__ bias,
    float* __restrict__ Y, int COUT, float* __restrict__ gout) {
    __shared__ __align__(16) unsigned short Xh[128 * 40];
    __shared__ __align__(16) unsigned short Xl[128 * 40];
    __shared__ __align__(16) unsigned short Wh[128 * 40];
    __shared__ __align__(16) unsigned short Wl[128 * 40];
    __shared__ float Gm[2][128];
    const int t = threadIdx.x;
    const int m0 = blockIdx.x * 128, o0 = blockIdx.y * 128;
    const int lane = t & 63, w = t >> 6;
    const int wr = (w >> 1) << 6, wc = (w & 1) << 6;
    const int lr = lane & 15, lg = lane >> 4;
    const int kb = lg << 3;
    const size_t WN = (size_t)COUT * Ktot;

    f32x4 acc[4][4];
    const f32x4 zz = {0.0f, 0.0f, 0.0f, 0.0f};
    #pragma unroll
    for (int i = 0; i < 4; ++i)
        #pragma unroll
        for (int j = 0; j < 4; ++j) acc[i][j] = zz;

    const int ntile = Ktot >> 5;
    for (int kt = 0; kt < ntile; ++kt) {
        const int kbase = kt << 5;
        const float* Xp; int S, koff;
        if (kbase < K1) { Xp = X1; S = S1; koff = kbase; }
        else            { Xp = X2; S = S2; koff = kbase - K1; }
        #pragma unroll
        for (int rr = 0; rr < 4; ++rr) {
            int idx = t + rr * 256;
            int p = idx >> 3, i4 = (idx & 7) << 2;
            const float4 v = *(const float4*)(Xp + (size_t)(m0 + p) * S + koff + i4);
            unsigned short h0 = bf16rne(v.x), h1 = bf16rne(v.y);
            unsigned short h2 = bf16rne(v.z), h3 = bf16rne(v.w);
            *(ushort4*)&Xh[p * 40 + i4] = make_ushort4(h0, h1, h2, h3);
            *(ushort4*)&Xl[p * 40 + i4] = make_ushort4(
                bf16rne(v.x - bff(h0)), bf16rne(v.y - bff(h1)),
                bf16rne(v.z - bff(h2)), bf16rne(v.w - bff(h3)));
        }
        #pragma unroll
        for (int rr = 0; rr < 2; ++rr) {
            int c = t + rr * 256;
            int o = c >> 2, k8 = (c & 3) << 3;
            const unsigned short* src = Wc + (size_t)(o0 + o) * Ktot + kbase + k8;
            *(uint4*)&Wh[o * 40 + k8] = *(const uint4*)src;
            *(uint4*)&Wl[o * 40 + k8] = *(const uint4*)(src + WN);
        }
        __syncthreads();

        bf16x8 ah[4], al[4], bh[4], bl[4];
        #pragma unroll
        for (int f = 0; f < 4; ++f) {
            ah[f] = *(const bf16x8*)&Xh[(wr + f * 16 + lr) * 40 + kb];
            al[f] = *(const bf16x8*)&Xl[(wr + f * 16 + lr) * 40 + kb];
            bh[f] = *(const bf16x8*)&Wh[(wc + f * 16 + lr) * 40 + kb];
            bl[f] = *(const bf16x8*)&Wl[(wc + f * 16 + lr) * 40 + kb];
        }
        #pragma unroll
        for (int i = 0; i < 4; ++i)
            #pragma unroll
            for (int j = 0; j < 4; ++j) {
                acc[i][j] = MF16(ah[i], bh[j], acc[i][j]);
                acc[i][j] = MF16(al[i], bh[j], acc[i][j]);
                acc[i][j] = MF16(ah[i], bl[j], acc[i][j]);
            }
        __syncthreads();
    }

    const int b = m0 >> 12;
    if (GMAX) {
        #pragma unroll
        for (int j = 0; j < 4; ++j) {
            const int oc = wc + j * 16 + lr;
            const float bv = bias[o0 + oc];
            float mx = 0.0f;
            #pragma unroll
            for (int i = 0; i < 4; ++i)
                #pragma unroll
                for (int r = 0; r < 4; ++r) {
                    float v = acc[i][j][r] + bv;
                    if (RELU) v = fmaxf(v, 0.0f);
                    mx = fmaxf(mx, v);
                }
            mx = fmaxf(mx, __shfl_xor(mx, 16));
            mx = fmaxf(mx, __shfl_xor(mx, 32));
            if (lane < 16) Gm[w >> 1][wc + j * 16 + lane] = mx;
        }
        __syncthreads();
        if (t < 128) {
            float v = fmaxf(Gm[0][t], Gm[1][t]);
            atomicMax((unsigned int*)(gout + b * 1024 + o0 + t), __float_as_uint(v));
        }
    } else {
        #pragma unroll
        for (int j = 0; j < 4; ++j) {
            const int oc = wc + j * 16 + lr;
            const float bv = (BMODE == 0) ? bias[o0 + oc] : bias[b * 512 + o0 + oc];
            #pragma unroll
            for (int i = 0; i < 4; ++i) {
                float* yp = Y + (size_t)(m0 + wr + i * 16 + lg * 4) * COUT + o0 + oc;
                #pragma unroll
                for (int r = 0; r < 4; ++r) {
                    float v = acc[i][j][r] + bv;
                    if (RELU) v = fmaxf(v, 0.0f);
                    yp[(size_t)r * COUT] = v;
                }
            }
        }
    }
}

// ---------------------------------------------------------------- bias3 = W_c3[:,160:] @ g + b_c3

__global__ void bias3_kernel(const float* __restrict__ g, const float* __restrict__ w_c3,
                             const float* __restrict__ b_c3, float* __restrict__ bias3) {
    __shared__ float gs[1024];
    int b = blockIdx.x >> 1;
    int o = ((blockIdx.x & 1) << 8) + threadIdx.x;
    for (int i = threadIdx.x; i < 1024; i += 256) gs[i] = g[b * 1024 + i];
    __syncthreads();
    float acc = b_c3[o];
    const float* wr = w_c3 + (size_t)o * 1184 + 160;
    for (int i = 0; i < 1024; i += 4) {
        float4 w4 = *(const float4*)(wr + i);
        acc = fmaf(w4.x, gs[i], acc);     acc = fmaf(w4.y, gs[i + 1], acc);
        acc = fmaf(w4.z, gs[i + 2], acc); acc = fmaf(w4.w, gs[i + 3], acc);
    }
    bias3[b * 512 + o] = acc;
}

// ---------------------------------------------------------------- final 128 -> 13 (no relu), output (B,13,N)

__global__ __launch_bounds__(256, 1) void c6_kernel(
    const float* __restrict__ h5, const float* __restrict__ w,
    const float* __restrict__ bias, float* __restrict__ out) {
    __shared__ float ws[13 * 128];
    __shared__ float bs[13];
    int t = threadIdx.x;
    for (int i = t; i < 13 * 128; i += 256) ws[i] = w[i];
    if (t < 13) bs[t] = bias[t];
    __syncthreads();
    int b = blockIdx.x >> 4;
    int n = ((blockIdx.x & 15) << 8) + t;
    float x[128];
    const float* xp = h5 + ((size_t)b * N_ + n) * 128;
    #pragma unroll
    for (int i = 0; i < 128; i += 4) *(float4*)&x[i] = *(const float4*)(xp + i);
    for (int o = 0; o < 13; ++o) {
        float acc = bs[o];
        #pragma unroll
        for (int i = 0; i < 128; ++i) acc = fmaf(ws[o * 128 + i], x[i], acc);
        out[((size_t)b * 13 + o) * N_ + n] = acc;
    }
}

// ---------------------------------------------------------------- launch

extern "C" void kernel_launch(void* const* d_in, const int* in_sizes, int n_in,
                              void* d_out, int out_size, void* d_ws, size_t ws_size,
                              hipStream_t stream) {
    (void)in_sizes; (void)n_in; (void)out_size; (void)ws_size;
    const float* xyz = (const float*)d_in[0];
    #define W_(j)  ((const float*)d_in[1 + 2 * (j)])
    #define Bp_(j) ((const float*)d_in[2 + 2 * (j)])

    char* ws = (char*)d_ws;
    const size_t MB = 1u << 20;
    int*   idx1  = (int*)(ws + 0 * MB);
    int*   idx2  = (int*)(ws + 2 * MB);
    float* fea1  = (float*)(ws + 4 * MB);
    float* CfPf  = (float*)(ws + 8 * MB);       // 32MB; overlays xyzp/feap planes; later h4
    float* fea2  = (float*)(ws + 40 * MB);
    float* h1    = (float*)(ws + 56 * MB);      // 16MB; reused later as h5
    float* sqbuf = (float*)(ws + 72 * MB);
    float* gbuf  = (float*)(ws + 72 * MB + (128u << 10));
    float* b3buf = (float*)(ws + 72 * MB + (160u << 10));
    float* wt    = (float*)(ws + 72 * MB + (176u << 10));
    float* h3    = (float*)(ws + 75 * MB);      // 64MB (also overlays knn Kbuf early)
    float* h4    = CfPf;
    float* h5    = h1;
    float* outp  = (float*)d_out;
    unsigned long long* Kbuf = (unsigned long long*)(ws + 75 * MB);
    unsigned short* xyzp = (unsigned short*)(ws + 8 * MB);    // 6MB, dead before CfPf written
    unsigned short* feap = (unsigned short*)(ws + 14 * MB);   // 6MB, dead before CfPf written

    // fp32 e1 weights + pre bias
    float* wte1  = wt;            // 3584
    float* bpre  = wt + 3584;     // 256
    // bf16 hi/lo planes ([o][k], lo at +numel)
    const unsigned short* wus = (const unsigned short*)(wt + 3840);
    const unsigned short* wpre = wus + 0;        // 256x32
    const unsigned short* wc1  = wus + 16384;    // 128x128
    const unsigned short* wc2  = wus + 49152;    // 1024x128
    const unsigned short* wc3  = wus + 311296;   // 512x160
    const unsigned short* wc4  = wus + 475136;   // 256x512
    const unsigned short* wc5  = wus + 737280;   // 128x256
    const unsigned short* wg1p = wus + 802816;   // 128x32 (padded)
    const unsigned short* wg2p = wus + 811008;   // 128x128
    const unsigned short* wf2p = wus + 843776;   // 128x128
    const unsigned short* wf3p = wus + 876544;   // 128x128

    prep_kernel<<<2079, 256, 0, stream>>>(
        W_(0), W_(1), W_(2), W_(3), W_(4), W_(5), W_(6), W_(8), W_(9), W_(10),
        W_(11), W_(12), W_(13), W_(14), W_(7), Bp_(7), xyz, wt, gbuf, sqbuf, xyzp);

    // knn1 + edgeconv1
    knn_kernel<<<dim3(64, 8, 2), 256, 0, stream>>>(xyzp, sqbuf, Kbuf);
    knn_merge_kernel<<<128, 256, 0, stream>>>(Kbuf, idx1);
    e1_kernel<<<4096, 256, 0, stream>>>(xyz, idx1, wte1, Bp_(0), Bp_(1), Bp_(2), Bp_(3), Bp_(4), fea1);

    // knn2 + edgeconv2
    fea1p_kernel<<<128, 256, 0, stream>>>(fea1, feap, sqbuf);
    knn_kernel<<<dim3(64, 8, 2), 256, 0, stream>>>(feap, sqbuf, Kbuf);
    knn_merge_kernel<<<128, 256, 0, stream>>>(Kbuf, idx2);
    gemm_mfma<0, 0, 0><<<dim3(256, 2), 256, 0, stream>>>(fea1, 32, 32, nullptr, 0, 32,
                                                         wpre, bpre, CfPf, 256, nullptr);
    e2_kernel<<<8192, 256, 0, stream>>>(xyz, idx2, CfPf, wg1p, wg2p, wf2p, wf3p,
                                        Bp_(5), Bp_(6), Bp_(8), Bp_(9), fea2);

    // head (split-bf16 MFMA)
    gemm_mfma<1, 0, 0><<<dim3(256, 1), 256, 0, stream>>>(fea2, 128, 128, nullptr, 0, 128,
                                                         wc1, Bp_(10), h1, 128, nullptr);
    gemm_mfma<1, 0, 1><<<dim3(256, 8), 256, 0, stream>>>(h1, 128, 128, nullptr, 0, 128,
                                                         wc2, Bp_(11), nullptr, 1024, gbuf);
    bias3_kernel<<<16, 256, 0, stream>>>(gbuf, W_(12), Bp_(12), b3buf);
    gemm_mfma<1, 1, 0><<<dim3(256, 4), 256, 0, stream>>>(fea1, 32, 32, fea2, 128, 160,
                                                         wc3, b3buf, h3, 512, nullptr);
    gemm_mfma<1, 0, 0><<<dim3(256, 2), 256, 0, stream>>>(h3, 512, 512, nullptr, 0, 512,
                                                         wc4, Bp_(13), h4, 256, nullptr);
    gemm_mfma<1, 0, 0><<<dim3(256, 1), 256, 0, stream>>>(h4, 256, 256, nullptr, 0, 256,
                                                         wc5, Bp_(14), h5, 128, nullptr);
    c6_kernel<<<128, 256, 0, stream>>>(h5, W_(15), Bp_(15), outp);
    #undef W_
    #undef Bp_
}

// Round 9
// 1047.502 us; speedup vs baseline: 1.2011x; 1.2011x over previous
//
#include <hip/hip_runtime.h>
#include <math.h>

#define B_ 8
#define N_ 4096
#define PL_ (8 * 4096 * 32)   // elements per bf16 plane (knn feature planes)

// ---------------------------------------------------------------- bf16 split helpers
__device__ __forceinline__ unsigned short bf16rne(float x) {
    unsigned int u = __float_as_uint(x);
    return (unsigned short)((u + 0x7FFFu + ((u >> 16) & 1u)) >> 16);
}
__device__ __forceinline__ float bff(unsigned short h) {
    return __uint_as_float((unsigned int)h << 16);
}
__device__ __forceinline__ void cvt_hl(unsigned short* base, int numel, int idx, float x) {
    unsigned short h = bf16rne(x);
    base[idx] = h;
    base[numel + idx] = bf16rne(x - bff(h));
}

typedef __attribute__((ext_vector_type(8))) short bf16x8;
typedef __attribute__((ext_vector_type(4))) float f32x4;

#define MF16(a, b, c) __builtin_amdgcn_mfma_f32_16x16x32_bf16((a), (b), (c), 0, 0, 0)

// ---------------------------------------------------------------- unified prep kernel
__global__ __launch_bounds__(256) void prep_kernel(
    const float* __restrict__ w0, const float* __restrict__ w1,
    const float* __restrict__ w2, const float* __restrict__ w3,
    const float* __restrict__ w4, const float* __restrict__ w5,
    const float* __restrict__ w6, const float* __restrict__ w8,
    const float* __restrict__ w9, const float* __restrict__ w10,
    const float* __restrict__ w11, const float* __restrict__ w12,
    const float* __restrict__ w13, const float* __restrict__ w14,
    const float* __restrict__ wf1, const float* __restrict__ bf1,
    const float* __restrict__ xyz,
    float* __restrict__ wt, float* __restrict__ gbuf, float* __restrict__ sqbuf,
    unsigned short* __restrict__ xyzp) {
    const int g = blockIdx.x * 256 + threadIdx.x;
    unsigned short* wus = (unsigned short*)(wt + 3840);

    if (g < 3584) {                              // e1 weights (fp32, [i][o])
        if (g < 320)       { int i = g >> 5, o = g & 31;             wt[g] = w0[o * 10 + i]; }
        else if (g < 1344) { int l = g - 320;  int i = l >> 5, o = l & 31; wt[g] = w1[o * 32 + i]; }
        else if (g < 1536) { int l = g - 1344; int i = l >> 5, o = l & 31; wt[g] = w2[o * 6 + i]; }
        else if (g < 2560) { int l = g - 1536; int i = l >> 5, o = l & 31; wt[g] = w3[o * 32 + i]; }
        else               { int l = g - 2560; int i = l >> 5, o = l & 31; wt[g] = w4[o * 32 + i]; }
    }
    else if (g < 3840)   { int l = g - 3584; wt[g] = (l < 128) ? bf1[l] : 0.0f; }                      // bpre
    else if (g < 12032)  { int l = g - 3840; int o = l >> 5, i = l & 31;                               // wpre 256x32
                           float x = (o < 128) ? wf1[o * 64 + i] : wf1[(o - 128) * 64 + 32 + i];
                           cvt_hl(wus + 0, 8192, l, x); }
    else if (g < 28416)  { int l = g - 12032;  cvt_hl(wus + 16384, 16384, l, w10[l]); }                // wc1 128x128
    else if (g < 159488) { int l = g - 28416;  cvt_hl(wus + 49152, 131072, l, w11[l]); }               // wc2 1024x128
    else if (g < 241408) { int l = g - 159488; int o = l / 160, i = l - o * 160;                       // wc3 512x160
                           cvt_hl(wus + 311296, 81920, l, w12[o * 1184 + i]); }
    else if (g < 372480) { int l = g - 241408; cvt_hl(wus + 475136, 131072, l, w13[l]); }              // wc4 256x512
    else if (g < 405248) { int l = g - 372480; cvt_hl(wus + 737280, 32768, l, w14[l]); }               // wc5 128x256
    else if (g < 409344) { int l = g - 405248; int o = l >> 5, k = l & 31;                             // wg1p 128x32 pad
                           float x = (k < 10) ? w5[o * 10 + k] : 0.0f;
                           cvt_hl(wus + 802816, 4096, l, x); }
    else if (g < 425728) { int l = g - 409344; cvt_hl(wus + 811008, 16384, l, w6[l]); }                // wg2p 128x128
    else if (g < 442112) { int l = g - 425728; cvt_hl(wus + 843776, 16384, l, w8[l]); }                // wf2p
    else if (g < 458496) { int l = g - 442112; cvt_hl(wus + 876544, 16384, l, w9[l]); }                // wf3p
    else if (g < 466688) { gbuf[g - 458496] = 0.0f; }
    else if (g < 499456) { int l = g - 466688;
                           const float* p = xyz + (size_t)l * 3;
                           sqbuf[l] = fmaf(p[0], p[0], fmaf(p[1], p[1], p[2] * p[2])); }
    else if (g < 532224) {                       // xyz h/m/l planes, K=32 zero-padded
        int row = g - 499456;
        const float* p = xyz + (size_t)row * 3;
        unsigned short hv[8] = {0,0,0,0,0,0,0,0};
        unsigned short mv[8] = {0,0,0,0,0,0,0,0};
        unsigned short lv[8] = {0,0,0,0,0,0,0,0};
        #pragma unroll
        for (int c = 0; c < 3; ++c) {
            float v = p[c];
            unsigned short h = bf16rne(v); float d = v - bff(h);
            unsigned short m = bf16rne(d);
            hv[c] = h; mv[c] = m; lv[c] = bf16rne(d - bff(m));
        }
        uint4 z = make_uint4(0u, 0u, 0u, 0u);
        unsigned short* d0 = xyzp + (size_t)row * 32;
        unsigned short* d1 = d0 + PL_;
        unsigned short* d2 = d0 + 2 * PL_;
        *(uint4*)d0 = *(uint4*)hv; *(uint4*)(d0 + 8) = z; *(uint4*)(d0 + 16) = z; *(uint4*)(d0 + 24) = z;
        *(uint4*)d1 = *(uint4*)mv; *(uint4*)(d1 + 8) = z; *(uint4*)(d1 + 16) = z; *(uint4*)(d1 + 24) = z;
        *(uint4*)d2 = *(uint4*)lv; *(uint4*)(d2 + 8) = z; *(uint4*)(d2 + 16) = z; *(uint4*)(d2 + 24) = z;
    }
}

// ---------------------------------------------------------------- fea1 -> h/m/l planes + sq (fused)
__global__ __launch_bounds__(256) void fea1p_kernel(
    const float* __restrict__ F, unsigned short* __restrict__ P, float* __restrict__ SQ) {
    int row = blockIdx.x * 256 + threadIdx.x;    // 32768 rows
    const float* x = F + (size_t)row * 32;
    float s = 0.0f;
    unsigned short hb[32], mb[32], lb[32];
    #pragma unroll
    for (int c = 0; c < 32; ++c) {
        float v = x[c];
        s = fmaf(v, v, s);
        unsigned short h = bf16rne(v); float d = v - bff(h);
        unsigned short m = bf16rne(d);
        hb[c] = h; mb[c] = m; lb[c] = bf16rne(d - bff(m));
    }
    SQ[row] = s;
    unsigned short* d0 = P + (size_t)row * 32;
    #pragma unroll
    for (int q = 0; q < 4; ++q) {
        *(uint4*)(d0 + 8 * q)           = *(uint4*)&hb[8 * q];
        *(uint4*)(d0 + PL_ + 8 * q)     = *(uint4*)&mb[8 * q];
        *(uint4*)(d0 + 2 * PL_ + 8 * q) = *(uint4*)&lb[8 * q];
    }
}

// ---------------------------------------------------------------- knn (top-16, MFMA two-pass)

__device__ __forceinline__ void cas_asc(unsigned long long& x, unsigned long long& y) {
    unsigned long long a = x, b = y;
    bool sw = a > b;
    x = sw ? b : a;
    y = sw ? a : b;
}

__device__ __forceinline__ void merge_top(unsigned long long (&k)[16],
                                          const unsigned long long (&o)[16]) {
    #pragma unroll
    for (int i = 0; i < 16; ++i) {
        unsigned long long bb = o[15 - i];
        if (bb > k[i]) k[i] = bb;
    }
    #pragma unroll
    for (int st = 8; st >= 1; st >>= 1)
        #pragma unroll
        for (int i = 0; i < 16; ++i)
            if ((i & st) == 0) cas_asc(k[i], k[i + st]);
}

__device__ __forceinline__ void casv(float& x, float& y) {
    float lo = fminf(x, y), hi = fmaxf(x, y);
    x = lo; y = hi;
}

__device__ __forceinline__ void sortv16(float (&v)[16]) {   // ascending
    #pragma unroll
    for (int sz = 2; sz <= 16; sz <<= 1)
        #pragma unroll
        for (int st = sz >> 1; st >= 1; st >>= 1)
            #pragma unroll
            for (int i = 0; i < 16; ++i)
                if ((i & st) == 0) {
                    if ((i & sz) == 0) casv(v[i], v[i + st]);
                    else                casv(v[i + st], v[i]);
                }
}

__device__ __forceinline__ void mergev(float (&kv)[16], const float (&nv)[16]) {
    #pragma unroll
    for (int i = 0; i < 16; ++i) kv[i] = fmaxf(kv[i], nv[15 - i]);
    #pragma unroll
    for (int st = 8; st >= 1; st >>= 1)
        #pragma unroll
        for (int i = 0; i < 16; ++i)
            if ((i & st) == 0) casv(kv[i], kv[i + st]);
}

__global__ __launch_bounds__(256, 4) void knn_kernel(
    const unsigned short* __restrict__ P, const float* __restrict__ SQ,
    unsigned long long* __restrict__ Kout) {
    __shared__ __align__(16) unsigned short Bs[3][64][40];   // 15360 B
    __shared__ __align__(16) char U[17408];                  // Ds (pass1, per-wave) | cap (pass2)
    __shared__ float tau_sm[64];
    __shared__ int cnt[64];
    const int t = threadIdx.x;
    const int b = blockIdx.y;
    const int r0 = blockIdx.x * 64;
    const int half = blockIdx.z;
    const int H0 = half * 2048;
    const int lane = t & 63, w = t >> 6;
    const int lr = lane & 15, lg = lane >> 4;
    const int kb = lg << 3;
    const int sc = t >> 2, sq8 = (t & 3) << 3;               // staging: col, ch-offset

    float* Ds = (float*)U + w * 1088;                        // [16][68] per wave
    unsigned long long* cap = (unsigned long long*)U;        // [64][32] (pass2 overlay)

    const unsigned short* ap = P + ((size_t)(b * N_) + r0 + 16 * w + lr) * 32 + kb;
    const bf16x8 ah = *(const bf16x8*)ap;
    const bf16x8 am = *(const bf16x8*)(ap + PL_);
    const bf16x8 al = *(const bf16x8*)(ap + 2 * PL_);
    const f32x4 sqr4 = *(const f32x4*)&SQ[(size_t)b * N_ + r0 + 16 * w + 4 * lg];

    const float* SQc = SQ + (size_t)b * N_ + H0;
    const unsigned short* Pc = P + ((size_t)(b * N_) + H0) * 32;

    uint4 sgh, sgm, sgl;                                     // staging registers
    auto issue = [&](int tt) {
        const unsigned short* src = Pc + (size_t)(tt * 64 + sc) * 32 + sq8;
        sgh = *(const uint4*)src;
        sgm = *(const uint4*)(src + PL_);
        sgl = *(const uint4*)(src + 2 * PL_);
    };
    auto commit = [&]() {
        *(uint4*)&Bs[0][sc][sq8] = sgh;
        *(uint4*)&Bs[1][sc][sq8] = sgm;
        *(uint4*)&Bs[2][sc][sq8] = sgl;
    };

    float kv[16];
    #pragma unroll
    for (int j = 0; j < 16; ++j) kv[j] = -3.4e38f;

    issue(0);
    // ---- pass 1 ----
    for (int tt = 0; tt < 32; ++tt) {
        commit();
        __syncthreads();                                     // Bs ready
        if (tt + 1 < 32) issue(tt + 1);                      // latency hides under compute
        #pragma unroll
        for (int j = 0; j < 4; ++j) {
            int cc = 16 * j + lr;
            bf16x8 bh = *(const bf16x8*)&Bs[0][cc][kb];
            bf16x8 bm = *(const bf16x8*)&Bs[1][cc][kb];
            bf16x8 bl = *(const bf16x8*)&Bs[2][cc][kb];
            f32x4 a = {0.0f, 0.0f, 0.0f, 0.0f};
            a = MF16(ah, bh, a); a = MF16(am, bh, a); a = MF16(ah, bm, a);
            a = MF16(am, bm, a); a = MF16(al, bh, a); a = MF16(ah, bl, a);
            float sqcv = SQc[tt * 64 + cc];
            #pragma unroll
            for (int r = 0; r < 4; ++r)
                Ds[(4 * lg + r) * 68 + cc] = fmaf(2.0f, a[r], -sqr4[r]) - sqcv;
        }
        float nv[16];
        #pragma unroll
        for (int q = 0; q < 4; ++q)
            *(float4*)&nv[4 * q] = *(const float4*)&Ds[lr * 68 + lg * 16 + 4 * q];
        sortv16(nv);
        mergev(kv, nv);
        __syncthreads();                                     // Bs reads done
    }
    issue(0);                                                // pass-2 tile 0 prefetch

    // ---- tau: merge 4 quarters across lanes (shfl), 16th value per row ----
    #pragma unroll
    for (int st = 16; st <= 32; st <<= 1) {
        float ov[16];
        #pragma unroll
        for (int i = 0; i < 16; ++i) ov[i] = __shfl_xor(kv[15 - i], st);
        #pragma unroll
        for (int i = 0; i < 16; ++i) kv[i] = fmaxf(kv[i], ov[i]);
        #pragma unroll
        for (int s2 = 8; s2 >= 1; s2 >>= 1)
            #pragma unroll
            for (int i = 0; i < 16; ++i)
                if ((i & s2) == 0) casv(kv[i], kv[i + s2]);
    }
    if (lane < 16) { tau_sm[w * 16 + lane] = kv[0]; cnt[w * 16 + lane] = 0; }
    const f32x4 taur4 = *(const f32x4*)&tau_sm[w * 16 + 4 * lg];

    // ---- pass 2: recompute, compact e >= tau ----
    for (int tt = 0; tt < 32; ++tt) {
        commit();
        __syncthreads();                                     // also guards Ds->cap overlay
        if (tt + 1 < 32) issue(tt + 1);
        #pragma unroll
        for (int j = 0; j < 4; ++j) {
            int cc = 16 * j + lr;
            bf16x8 bh = *(const bf16x8*)&Bs[0][cc][kb];
            bf16x8 bm = *(const bf16x8*)&Bs[1][cc][kb];
            bf16x8 bl = *(const bf16x8*)&Bs[2][cc][kb];
            f32x4 a = {0.0f, 0.0f, 0.0f, 0.0f};
            a = MF16(ah, bh, a); a = MF16(am, bh, a); a = MF16(ah, bm, a);
            a = MF16(am, bm, a); a = MF16(al, bh, a); a = MF16(ah, bl, a);
            float sqcv = SQc[tt * 64 + cc];
            #pragma unroll
            for (int r = 0; r < 4; ++r) {
                float e = fmaf(2.0f, a[r], -sqr4[r]) - sqcv;
                if (e >= taur4[r]) {
                    int row = 16 * w + 4 * lg + r;
                    unsigned int u = __float_as_uint(e);
                    unsigned int ou = (u & 0x80000000u) ? ~u : (u | 0x80000000u);
                    unsigned long long key = ((unsigned long long)ou << 32)
                                           | (unsigned int)(4095 - (H0 + tt * 64 + cc));
                    int pos = atomicAdd(&cnt[row], 1);
                    if (pos < 32) cap[row * 32 + pos] = key;
                }
            }
        }
        __syncthreads();
    }

    // ---- final per-row exact top-16 (u64 keys, asc) ----
    if (t < 64) {
        int n = min(cnt[t], 32);
        unsigned long long K[16];
        #pragma unroll
        for (int j = 0; j < 16; ++j) K[j] = 0ull;
        for (int i = 0; i < n; ++i) {
            unsigned long long v = cap[t * 32 + i];
            if (v > K[0]) {
                K[0] = v;
                #pragma unroll
                for (int s = 0; s < 15; ++s) cas_asc(K[s], K[s + 1]);
            }
        }
        size_t obase = (((size_t)b * 2 + half) * N_ + r0 + t) * 16;
        #pragma unroll
        for (int j = 0; j < 16; ++j) Kout[obase + j] = K[j];
    }
}

__global__ __launch_bounds__(256) void knn_merge_kernel(
    const unsigned long long* __restrict__ Kbuf, int* __restrict__ IDX) {
    int gid = blockIdx.x * 256 + threadIdx.x;
    int b = gid >> 12, r = gid & 4095;
    unsigned long long K0[16], K1[16];
    const unsigned long long* p0 = Kbuf + (((size_t)b * 2 + 0) * N_ + r) * 16;
    const unsigned long long* p1 = Kbuf + (((size_t)b * 2 + 1) * N_ + r) * 16;
    #pragma unroll
    for (int j = 0; j < 16; ++j) { K0[j] = p0[j]; K1[j] = p1[j]; }
    merge_top(K0, K1);
    size_t ob = ((size_t)b * N_ + r) * 16;
    #pragma unroll
    for (int j = 0; j < 16; ++j)
        IDX[ob + j] = 4095 - (int)(unsigned int)(K0[15 - j] & 0xFFFFFFFFu);
}

// ---------------------------------------------------------------- edgeconv 1 (xyz, C=3 -> 32)

__global__ __launch_bounds__(256, 4) void e1_kernel(
    const float* __restrict__ xyz, const int* __restrict__ idx1,
    const float* __restrict__ wte1,
    const float* __restrict__ bg1, const float* __restrict__ bg2,
    const float* __restrict__ bf1, const float* __restrict__ bf2,
    const float* __restrict__ bf3,
    float* __restrict__ fea1) {
    __shared__ __align__(16) float Ain[10 * 132];
    __shared__ __align__(16) float Bu0[32 * 132];
    __shared__ __align__(16) float Bu1[32 * 132];
    __shared__ __align__(16) float wl[3584];
    __shared__ float bl[5][32];
    __shared__ __align__(16) float Pm1[4][8][32];
    __shared__ int idxl[128];
    const int t = threadIdx.x;
    const int b = blockIdx.x >> 9;
    const int n0 = (blockIdx.x & 511) << 3;
    const int et = (t & 31) << 2;
    const int ct = (t >> 5) << 2;

    for (int i = t; i < 3584; i += 256) wl[i] = wte1[i];
    if (t < 32) {
        bl[0][t] = bg1[t]; bl[1][t] = bg2[t]; bl[2][t] = bf1[t];
        bl[3][t] = bf2[t]; bl[4][t] = bf3[t];
    }
    if (t < 128) idxl[t] = idx1[((size_t)b * N_ + n0 + (t >> 4)) * 16 + (t & 15)];
    __syncthreads();
    if (t < 128) {
        int p = t >> 4, n = n0 + p, m = idxl[t];
        const float* xc = xyz + ((size_t)b * N_ + n) * 3;
        const float* xk = xyz + ((size_t)b * N_ + m) * 3;
        float c0 = xc[0], c1v = xc[1], c2v = xc[2];
        float k0 = xk[0], k1 = xk[1], k2 = xk[2];
        float r0 = c0 - k0, r1 = c1v - k1, r2 = c2v - k2;
        Ain[0 * 132 + t] = sqrtf(r0 * r0 + r1 * r1 + r2 * r2);
        Ain[1 * 132 + t] = c0;  Ain[2 * 132 + t] = c1v; Ain[3 * 132 + t] = c2v;
        Ain[4 * 132 + t] = k0;  Ain[5 * 132 + t] = k1;  Ain[6 * 132 + t] = k2;
        Ain[7 * 132 + t] = r0;  Ain[8 * 132 + t] = r1;  Ain[9 * 132 + t] = r2;
    }
    __syncthreads();

    float acc[4][4];
    auto gem = [&](int KK, const float* Asrc, int woff) {
        #pragma unroll
        for (int ii = 0; ii < 4; ++ii)
            #pragma unroll
            for (int jj = 0; jj < 4; ++jj) acc[ii][jj] = 0.0f;
        for (int i = 0; i < KK; ++i) {
            float a4[4], w4[4];
            *(float4*)a4 = *(const float4*)&Asrc[i * 132 + et];
            *(float4*)w4 = *(const float4*)&wl[woff + i * 32 + ct];
            #pragma unroll
            for (int ii = 0; ii < 4; ++ii)
                #pragma unroll
                for (int jj = 0; jj < 4; ++jj)
                    acc[ii][jj] = fmaf(a4[ii], w4[jj], acc[ii][jj]);
        }
    };
    auto wrout = [&](float* dst, const float* brow) {
        #pragma unroll
        for (int jj = 0; jj < 4; ++jj) {
            float tmp[4];
            #pragma unroll
            for (int ii = 0; ii < 4; ++ii) tmp[ii] = fmaxf(acc[ii][jj] + brow[ct + jj], 0.0f);
            *(float4*)&dst[(ct + jj) * 132 + et] = *(float4*)tmp;
        }
    };

    gem(10, Ain, 0);          wrout(Bu1, bl[0]);   __syncthreads();
    gem(32, Bu1, 320);
    float g2r[4][4];
    #pragma unroll
    for (int ii = 0; ii < 4; ++ii)
        #pragma unroll
        for (int jj = 0; jj < 4; ++jj)
            g2r[ii][jj] = fmaxf(acc[ii][jj] + bl[1][ct + jj], 0.0f);
    gem(6, Ain + 132, 1344);  wrout(Bu0, bl[2]);   __syncthreads();
    gem(32, Bu0, 1536);       wrout(Bu1, bl[3]);   __syncthreads();
    gem(32, Bu1, 2560);

    float pm[4];
    #pragma unroll
    for (int jj = 0; jj < 4; ++jj) {
        float mx = 0.0f;
        #pragma unroll
        for (int ii = 0; ii < 4; ++ii) {
            float f3 = fmaxf(acc[ii][jj] + bl[4][ct + jj], 0.0f);
            mx = fmaxf(mx, g2r[ii][jj] * f3);
        }
        pm[jj] = mx;
    }
    const int sub = t & 3, pl = (t & 31) >> 2;
    *(float4*)&Pm1[sub][pl][ct] = *(float4*)pm;
    __syncthreads();
    {
        int p = t >> 5, c = t & 31;
        float v = fmaxf(fmaxf(Pm1[0][p][c], Pm1[1][p][c]), fmaxf(Pm1[2][p][c], Pm1[3][p][c]));
        fea1[((size_t)b * N_ + n0 + p) * 32 + c] = v;
    }
}

// ---------------------------------------------------------------- edgeconv 2 (split-bf16 MFMA, o-quarter waves)
// 8 points / 128 edges per block, 256 threads, 4 waves. Wave w owns o-quarter
// [32w, 32w+32) x ALL 128 edges: per-wave W traffic halves vs the 64x64 split
// (W panels disjoint across waves), per-wave MFMA count unchanged (192/gemmK).
// Per-accumulator MFMA sequence identical -> bit-identical results.

__global__ __launch_bounds__(256, 2) void e2_kernel(
    const float* __restrict__ xyz, const int* __restrict__ idx2,
    const float* __restrict__ CfPf,
    const unsigned short* __restrict__ wg1p, const unsigned short* __restrict__ wg2p,
    const unsigned short* __restrict__ wf2p, const unsigned short* __restrict__ wf3p,
    const float* __restrict__ bg1, const float* __restrict__ bg2,
    const float* __restrict__ bf2, const float* __restrict__ bf3,
    float* __restrict__ fea2) {
    __shared__ __align__(16) unsigned short Ah[128 * 128];   // 32KB hi plane [e][ch]
    __shared__ __align__(16) unsigned short Al[128 * 128];   // 32KB lo plane
    __shared__ float bb[4][128];
    __shared__ int idxl[128];
    const int t = threadIdx.x;
    const int b = blockIdx.x >> 9;
    const int n0 = (blockIdx.x & 511) << 3;
    const int lane = t & 63, w = t >> 6;
    const int wr = w << 5;           // o quarter: 0/32/64/96
    const int lr = lane & 15, lg = lane >> 4;
    const int kb = lg << 3;

    auto swz = [](int e, int bo) { return e * 256 + (bo ^ ((e & 7) << 4)); };

    for (int i = t; i < 512; i += 256) {
        const float* bp = (i < 128) ? bg1 : (i < 256) ? bg2 : (i < 384) ? bf2 : bf3;
        bb[i >> 7][i & 127] = bp[i & 127];
    }
    if (t < 128) idxl[t] = idx2[((size_t)b * N_ + n0 + (t >> 4)) * 16 + (t & 15)];
    __syncthreads();

    f32x4 acc[2][8];
    const f32x4 zz = {0.0f, 0.0f, 0.0f, 0.0f};
    auto zacc = [&]() {
        #pragma unroll
        for (int i = 0; i < 2; ++i)
            #pragma unroll
            for (int j = 0; j < 8; ++j) acc[i][j] = zz;
    };

    {   // ---- g1: per-j geometry B-fragment in registers, K=32 (10 real + 22 zero) ----
        zacc();
        bf16x8 wh[2], wl_[2];
        #pragma unroll
        for (int i = 0; i < 2; ++i) {
            size_t off = (size_t)(wr + i * 16 + lr) * 32 + kb;
            wh[i] = *(const bf16x8*)(wg1p + off);
            wl_[i] = *(const bf16x8*)(wg1p + 4096 + off);
        }
        #pragma unroll
        for (int j = 0; j < 8; ++j) {
            float gv[8];
            #pragma unroll
            for (int q = 0; q < 8; ++q) gv[q] = 0.0f;
            if (lg < 2) {
                int e = j * 16 + lr;
                int p = e >> 4, m = idxl[e];
                const float* xc = xyz + ((size_t)b * N_ + n0 + p) * 3;
                const float* xk = xyz + ((size_t)b * N_ + m) * 3;
                float c0 = xc[0], c1 = xc[1], c2 = xc[2];
                float k0 = xk[0], k1 = xk[1], k2 = xk[2];
                float r0 = c0 - k0, r1 = c1 - k1, r2 = c2 - k2;
                if (lg == 0) {
                    gv[0] = sqrtf(r0 * r0 + r1 * r1 + r2 * r2);
                    gv[1] = c0; gv[2] = c1; gv[3] = c2;
                    gv[4] = k0; gv[5] = k1; gv[6] = k2; gv[7] = r0;
                } else { gv[0] = r1; gv[1] = r2; }
            }
            bf16x8 gbh, gbl;
            #pragma unroll
            for (int q = 0; q < 8; ++q) {
                unsigned short h = bf16rne(gv[q]);
                gbh[q] = (short)h;
                gbl[q] = (short)bf16rne(gv[q] - bff(h));
            }
            #pragma unroll
            for (int i = 0; i < 2; ++i) {
                acc[i][j] = MF16(wh[i], gbh, acc[i][j]);
                acc[i][j] = MF16(wl_[i], gbh, acc[i][j]);
                acc[i][j] = MF16(wh[i], gbl, acc[i][j]);
            }
        }
    }

    // epilogue: relu(acc + bias) -> hi/lo planes at [e][o]
    auto epi_store = [&](const float* brow) {
        #pragma unroll
        for (int i = 0; i < 2; ++i) {
            int o4 = wr + i * 16 + lg * 4;
            float bv[4];
            *(float4*)bv = *(const float4*)&brow[o4];
            #pragma unroll
            for (int j = 0; j < 8; ++j) {
                int e = j * 16 + lr;
                unsigned short h[4], l[4];
                #pragma unroll
                for (int r = 0; r < 4; ++r) {
                    float v = fmaxf(acc[i][j][r] + bv[r], 0.0f);
                    h[r] = bf16rne(v);
                    l[r] = bf16rne(v - bff(h[r]));
                }
                int bo = swz(e, o4 * 2);
                *(ushort4*)((char*)Ah + bo) = make_ushort4(h[0], h[1], h[2], h[3]);
                *(ushort4*)((char*)Al + bo) = make_ushort4(l[0], l[1], l[2], l[3]);
            }
        }
    };
    epi_store(bb[0]);
    __syncthreads();

    // K=128 GEMM: W (o-quarter panel) from global, activations from swizzled LDS planes.
    // x-fragments processed in j-halves to bound register liveness.
    auto gemmK = [&](const unsigned short* __restrict__ Wp) {
        zacc();
        #pragma unroll
        for (int ks = 0; ks < 4; ++ks) {
            bf16x8 wh[2], wl_[2];
            #pragma unroll
            for (int i = 0; i < 2; ++i) {
                size_t off = (size_t)(wr + i * 16 + lr) * 128 + ks * 32 + kb;
                wh[i] = *(const bf16x8*)(Wp + off);
                wl_[i] = *(const bf16x8*)(Wp + 16384 + off);
            }
            #pragma unroll
            for (int jh = 0; jh < 2; ++jh) {
                bf16x8 xh[4], xl[4];
                #pragma unroll
                for (int jj = 0; jj < 4; ++jj) {
                    int e = (jh * 4 + jj) * 16 + lr;
                    int bo = swz(e, (ks * 32 + kb) * 2);
                    xh[jj] = *(const bf16x8*)((const char*)Ah + bo);
                    xl[jj] = *(const bf16x8*)((const char*)Al + bo);
                }
                #pragma unroll
                for (int i = 0; i < 2; ++i) {
                    #pragma unroll
                    for (int jj = 0; jj < 4; ++jj) {
                        int j = jh * 4 + jj;
                        acc[i][j] = MF16(wh[i], xh[jj], acc[i][j]);
                        acc[i][j] = MF16(wl_[i], xh[jj], acc[i][j]);
                        acc[i][j] = MF16(wh[i], xl[jj], acc[i][j]);
                    }
                }
            }
        }
    };

    gemmK(wg2p);
    float g2r[2][8][4];
    #pragma unroll
    for (int i = 0; i < 2; ++i) {
        float bv[4];
        *(float4*)bv = *(const float4*)&bb[1][wr + i * 16 + lg * 4];
        #pragma unroll
        for (int j = 0; j < 8; ++j)
            #pragma unroll
            for (int r = 0; r < 4; ++r)
                g2r[i][j][r] = fmaxf(acc[i][j][r] + bv[r], 0.0f);
    }
    __syncthreads();

    {   // ---- f1: gather relu(Cf[n] + Pf[m]) -> planes ----
        int e = t & 127, hf = t >> 7;
        int n = n0 + (e >> 4), m = idxl[e];
        const float* crow = CfPf + ((size_t)b * N_ + n) * 256 + hf * 64;
        const float* prow = CfPf + ((size_t)b * N_ + m) * 256 + 128 + hf * 64;
        #pragma unroll
        for (int q = 0; q < 16; ++q) {
            float4 cc = *(const float4*)(crow + q * 4);
            float4 pp = *(const float4*)(prow + q * 4);
            float v[4] = { fmaxf(cc.x + pp.x, 0.0f), fmaxf(cc.y + pp.y, 0.0f),
                           fmaxf(cc.z + pp.z, 0.0f), fmaxf(cc.w + pp.w, 0.0f) };
            unsigned short h[4], l[4];
            #pragma unroll
            for (int r = 0; r < 4; ++r) {
                h[r] = bf16rne(v[r]);
                l[r] = bf16rne(v[r] - bff(h[r]));
            }
            int bo = swz(e, (hf * 64 + q * 4) * 2);
            *(ushort4*)((char*)Ah + bo) = make_ushort4(h[0], h[1], h[2], h[3]);
            *(ushort4*)((char*)Al + bo) = make_ushort4(l[0], l[1], l[2], l[3]);
        }
    }
    __syncthreads();

    gemmK(wf2p);
    __syncthreads();
    epi_store(bb[2]);
    __syncthreads();

    gemmK(wf3p);
    #pragma unroll
    for (int j = 0; j < 8; ++j) {
        int p = j;                       // point within block (0..7)
        #pragma unroll
        for (int i = 0; i < 2; ++i) {
            int o4 = wr + i * 16 + lg * 4;
            float bv[4];
            *(float4*)bv = *(const float4*)&bb[3][o4];
            float vr[4];
            #pragma unroll
            for (int r = 0; r < 4; ++r) {
                float f3v = fmaxf(acc[i][j][r] + bv[r], 0.0f);
                float v = g2r[i][j][r] * f3v;
                v = fmaxf(v, __shfl_xor(v, 1));
                v = fmaxf(v, __shfl_xor(v, 2));
                v = fmaxf(v, __shfl_xor(v, 4));
                v = fmaxf(v, __shfl_xor(v, 8));
                vr[r] = v;
            }
            if (lr == 0)
                *(float4*)(fea2 + ((size_t)b * N_ + n0 + p) * 128 + o4) = *(float4*)vr;
        }
    }
}

// ---------------------------------------------------------------- split-bf16 MFMA pointwise GEMM (head)

template<int RELU, int BMODE, int GMAX>
__global__ __launch_bounds__(256) void gemm_mfma(
    const float* __restrict__ X1, int S1, int K1,
    const float* __restrict__ X2, int S2, int Ktot,
    const unsigned short* __restrict__ Wc, const float* __restrict__ bias,
    float* __restrict__ Y, int COUT, float* __restrict__ gout) {
    __shared__ __align__(16) unsigned short Xh[128 * 40];
    __shared__ __align__(16) unsigned short Xl[128 * 40];
    __shared__ __align__(16) unsigned short Wh[128 * 40];
    __shared__ __align__(16) unsigned short Wl[128 * 40];
    __shared__ float Gm[2][128];
    const int t = threadIdx.x;
    const int m0 = blockIdx.x * 128, o0 = blockIdx.y * 128;
    const int lane = t & 63, w = t >> 6;
    const int wr = (w >> 1) << 6, wc = (w & 1) << 6;
    const int lr = lane & 15, lg = lane >> 4;
    const int kb = lg << 3;
    const size_t WN = (size_t)COUT * Ktot;

    f32x4 acc[4][4];
    const f32x4 zz = {0.0f, 0.0f, 0.0f, 0.0f};
    #pragma unroll
    for (int i = 0; i < 4; ++i)
        #pragma unroll
        for (int j = 0; j < 4; ++j) acc[i][j] = zz;

    const int ntile = Ktot >> 5;
    for (int kt = 0; kt < ntile; ++kt) {
        const int kbase = kt << 5;
        const float* Xp; int S, koff;
        if (kbase < K1) { Xp = X1; S = S1; koff = kbase; }
        else            { Xp = X2; S = S2; koff = kbase - K1; }
        #pragma unroll
        for (int rr = 0; rr < 4; ++rr) {
            int idx = t + rr * 256;
            int p = idx >> 3, i4 = (idx & 7) << 2;
            const float4 v = *(const float4*)(Xp + (size_t)(m0 + p) * S + koff + i4);
            unsigned short h0 = bf16rne(v.x), h1 = bf16rne(v.y);
            unsigned short h2 = bf16rne(v.z), h3 = bf16rne(v.w);
            *(ushort4*)&Xh[p * 40 + i4] = make_ushort4(h0, h1, h2, h3);
            *(ushort4*)&Xl[p * 40 + i4] = make_ushort4(
                bf16rne(v.x - bff(h0)), bf16rne(v.y - bff(h1)),
                bf16rne(v.z - bff(h2)), bf16rne(v.w - bff(h3)));
        }
        #pragma unroll
        for (int rr = 0; rr < 2; ++rr) {
            int c = t + rr * 256;
            int o = c >> 2, k8 = (c & 3) << 3;
            const unsigned short* src = Wc + (size_t)(o0 + o) * Ktot + kbase + k8;
            *(uint4*)&Wh[o * 40 + k8] = *(const uint4*)src;
            *(uint4*)&Wl[o * 40 + k8] = *(const uint4*)(src + WN);
        }
        __syncthreads();

        bf16x8 ah[4], al[4], bh[4], bl[4];
        #pragma unroll
        for (int f = 0; f < 4; ++f) {
            ah[f] = *(const bf16x8*)&Xh[(wr + f * 16 + lr) * 40 + kb];
            al[f] = *(const bf16x8*)&Xl[(wr + f * 16 + lr) * 40 + kb];
            bh[f] = *(const bf16x8*)&Wh[(wc + f * 16 + lr) * 40 + kb];
            bl[f] = *(const bf16x8*)&Wl[(wc + f * 16 + lr) * 40 + kb];
        }
        #pragma unroll
        for (int i = 0; i < 4; ++i)
            #pragma unroll
            for (int j = 0; j < 4; ++j) {
                acc[i][j] = MF16(ah[i], bh[j], acc[i][j]);
                acc[i][j] = MF16(al[i], bh[j], acc[i][j]);
                acc[i][j] = MF16(ah[i], bl[j], acc[i][j]);
            }
        __syncthreads();
    }

    const int b = m0 >> 12;
    if (GMAX) {
        #pragma unroll
        for (int j = 0; j < 4; ++j) {
            const int oc = wc + j * 16 + lr;
            const float bv = bias[o0 + oc];
            float mx = 0.0f;
            #pragma unroll
            for (int i = 0; i < 4; ++i)
                #pragma unroll
                for (int r = 0; r < 4; ++r) {
                    float v = acc[i][j][r] + bv;
                    if (RELU) v = fmaxf(v, 0.0f);
                    mx = fmaxf(mx, v);
                }
            mx = fmaxf(mx, __shfl_xor(mx, 16));
            mx = fmaxf(mx, __shfl_xor(mx, 32));
            if (lane < 16) Gm[w >> 1][wc + j * 16 + lane] = mx;
        }
        __syncthreads();
        if (t < 128) {
            float v = fmaxf(Gm[0][t], Gm[1][t]);
            atomicMax((unsigned int*)(gout + b * 1024 + o0 + t), __float_as_uint(v));
        }
    } else {
        #pragma unroll
        for (int j = 0; j < 4; ++j) {
            const int oc = wc + j * 16 + lr;
            const float bv = (BMODE == 0) ? bias[o0 + oc] : bias[b * 512 + o0 + oc];
            #pragma unroll
            for (int i = 0; i < 4; ++i) {
                float* yp = Y + (size_t)(m0 + wr + i * 16 + lg * 4) * COUT + o0 + oc;
                #pragma unroll
                for (int r = 0; r < 4; ++r) {
                    float v = acc[i][j][r] + bv;
                    if (RELU) v = fmaxf(v, 0.0f);
                    yp[(size_t)r * COUT] = v;
                }
            }
        }
    }
}

// ---------------------------------------------------------------- bias3 = W_c3[:,160:] @ g + b_c3

__global__ void bias3_kernel(const float* __restrict__ g, const float* __restrict__ w_c3,
                             const float* __restrict__ b_c3, float* __restrict__ bias3) {
    __shared__ float gs[1024];
    int b = blockIdx.x >> 1;
    int o = ((blockIdx.x & 1) << 8) + threadIdx.x;
    for (int i = threadIdx.x; i < 1024; i += 256) gs[i] = g[b * 1024 + i];
    __syncthreads();
    float acc = b_c3[o];
    const float* wr = w_c3 + (size_t)o * 1184 + 160;
    for (int i = 0; i < 1024; i += 4) {
        float4 w4 = *(const float4*)(wr + i);
        acc = fmaf(w4.x, gs[i], acc);     acc = fmaf(w4.y, gs[i + 1], acc);
        acc = fmaf(w4.z, gs[i + 2], acc); acc = fmaf(w4.w, gs[i + 3], acc);
    }
    bias3[b * 512 + o] = acc;
}

// ---------------------------------------------------------------- final 128 -> 13 (no relu), output (B,13,N)

__global__ __launch_bounds__(256, 1) void c6_kernel(
    const float* __restrict__ h5, const float* __restrict__ w,
    const float* __restrict__ bias, float* __restrict__ out) {
    __shared__ float ws[13 * 128];
    __shared__ float bs[13];
    int t = threadIdx.x;
    for (int i = t; i < 13 * 128; i += 256) ws[i] = w[i];
    if (t < 13) bs[t] = bias[t];
    __syncthreads();
    int b = blockIdx.x >> 4;
    int n = ((blockIdx.x & 15) << 8) + t;
    float x[128];
    const float* xp = h5 + ((size_t)b * N_ + n) * 128;
    #pragma unroll
    for (int i = 0; i < 128; i += 4) *(float4*)&x[i] = *(const float4*)(xp + i);
    for (int o = 0; o < 13; ++o) {
        float acc = bs[o];
        #pragma unroll
        for (int i = 0; i < 128; ++i) acc = fmaf(ws[o * 128 + i], x[i], acc);
        out[((size_t)b * 13 + o) * N_ + n] = acc;
    }
}

// ---------------------------------------------------------------- launch

extern "C" void kernel_launch(void* const* d_in, const int* in_sizes, int n_in,
                              void* d_out, int out_size, void* d_ws, size_t ws_size,
                              hipStream_t stream) {
    (void)in_sizes; (void)n_in; (void)out_size; (void)ws_size;
    const float* xyz = (const float*)d_in[0];
    #define W_(j)  ((const float*)d_in[1 + 2 * (j)])
    #define Bp_(j) ((const float*)d_in[2 + 2 * (j)])

    char* ws = (char*)d_ws;
    const size_t MB = 1u << 20;
    int*   idx1  = (int*)(ws + 0 * MB);
    int*   idx2  = (int*)(ws + 2 * MB);
    float* fea1  = (float*)(ws + 4 * MB);
    float* CfPf  = (float*)(ws + 8 * MB);       // 32MB; overlays xyzp/feap planes; later h4
    float* fea2  = (float*)(ws + 40 * MB);
    float* h1    = (float*)(ws + 56 * MB);      // 16MB; reused later as h5
    float* sqbuf = (float*)(ws + 72 * MB);
    float* gbuf  = (float*)(ws + 72 * MB + (128u << 10));
    float* b3buf = (float*)(ws + 72 * MB + (160u << 10));
    float* wt    = (float*)(ws + 72 * MB + (176u << 10));
    float* h3    = (float*)(ws + 75 * MB);      // 64MB (also overlays knn Kbuf early)
    float* h4    = CfPf;
    float* h5    = h1;
    float* outp  = (float*)d_out;
    unsigned long long* Kbuf = (unsigned long long*)(ws + 75 * MB);
    unsigned short* xyzp = (unsigned short*)(ws + 8 * MB);    // 6MB, dead before CfPf written
    unsigned short* feap = (unsigned short*)(ws + 14 * MB);   // 6MB, dead before CfPf written

    // fp32 e1 weights + pre bias
    float* wte1  = wt;            // 3584
    float* bpre  = wt + 3584;     // 256
    // bf16 hi/lo planes ([o][k], lo at +numel)
    const unsigned short* wus = (const unsigned short*)(wt + 3840);
    const unsigned short* wpre = wus + 0;        // 256x32
    const unsigned short* wc1  = wus + 16384;    // 128x128
    const unsigned short* wc2  = wus + 49152;    // 1024x128
    const unsigned short* wc3  = wus + 311296;   // 512x160
    const unsigned short* wc4  = wus + 475136;   // 256x512
    const unsigned short* wc5  = wus + 737280;   // 128x256
    const unsigned short* wg1p = wus + 802816;   // 128x32 (padded)
    const unsigned short* wg2p = wus + 811008;   // 128x128
    const unsigned short* wf2p = wus + 843776;   // 128x128
    const unsigned short* wf3p = wus + 876544;   // 128x128

    prep_kernel<<<2079, 256, 0, stream>>>(
        W_(0), W_(1), W_(2), W_(3), W_(4), W_(5), W_(6), W_(8), W_(9), W_(10),
        W_(11), W_(12), W_(13), W_(14), W_(7), Bp_(7), xyz, wt, gbuf, sqbuf, xyzp);

    // knn1 + edgeconv1
    knn_kernel<<<dim3(64, 8, 2), 256, 0, stream>>>(xyzp, sqbuf, Kbuf);
    knn_merge_kernel<<<128, 256, 0, stream>>>(Kbuf, idx1);
    e1_kernel<<<4096, 256, 0, stream>>>(xyz, idx1, wte1, Bp_(0), Bp_(1), Bp_(2), Bp_(3), Bp_(4), fea1);

    // knn2 + edgeconv2
    fea1p_kernel<<<128, 256, 0, stream>>>(fea1, feap, sqbuf);
    knn_kernel<<<dim3(64, 8, 2), 256, 0, stream>>>(feap, sqbuf, Kbuf);
    knn_merge_kernel<<<128, 256, 0, stream>>>(Kbuf, idx2);
    gemm_mfma<0, 0, 0><<<dim3(256, 2), 256, 0, stream>>>(fea1, 32, 32, nullptr, 0, 32,
                                                         wpre, bpre, CfPf, 256, nullptr);
    e2_kernel<<<4096, 256, 0, stream>>>(xyz, idx2, CfPf, wg1p, wg2p, wf2p, wf3p,
                                        Bp_(5), Bp_(6), Bp_(8), Bp_(9), fea2);

    // head (split-bf16 MFMA)
    gemm_mfma<1, 0, 0><<<dim3(256, 1), 256, 0, stream>>>(fea2, 128, 128, nullptr, 0, 128,
                                                         wc1, Bp_(10), h1, 128, nullptr);
    gemm_mfma<1, 0, 1><<<dim3(256, 8), 256, 0, stream>>>(h1, 128, 128, nullptr, 0, 128,
                                                         wc2, Bp_(11), nullptr, 1024, gbuf);
    bias3_kernel<<<16, 256, 0, stream>>>(gbuf, W_(12), Bp_(12), b3buf);
    gemm_mfma<1, 1, 0><<<dim3(256, 4), 256, 0, stream>>>(fea1, 32, 32, fea2, 128, 160,
                                                         wc3, b3buf, h3, 512, nullptr);
    gemm_mfma<1, 0, 0><<<dim3(256, 2), 256, 0, stream>>>(h3, 512, 512, nullptr, 0, 512,
                                                         wc4, Bp_(13), h4, 256, nullptr);
    gemm_mfma<1, 0, 0><<<dim3(256, 1), 256, 0, stream>>>(h4, 256, 256, nullptr, 0, 256,
                                                         wc5, Bp_(14), h5, 128, nullptr);
    c6_kernel<<<128, 256, 0, stream>>>(h5, W_(15), Bp_(15), outp);
    #undef W_
    #undef Bp_
}

// Round 10
// 1045.488 us; speedup vs baseline: 1.2034x; 1.0019x over previous
//
#include <hip/hip_runtime.h>
#include <math.h>

#define B_ 8
#define N_ 4096
#define PL_ (8 * 4096 * 32)   // elements per bf16 plane (knn feature planes)

// ---------------------------------------------------------------- bf16 split helpers
__device__ __forceinline__ unsigned short bf16rne(float x) {
    unsigned int u = __float_as_uint(x);
    return (unsigned short)((u + 0x7FFFu + ((u >> 16) & 1u)) >> 16);
}
__device__ __forceinline__ float bff(unsigned short h) {
    return __uint_as_float((unsigned int)h << 16);
}
__device__ __forceinline__ void cvt_hl(unsigned short* base, int numel, int idx, float x) {
    unsigned short h = bf16rne(x);
    base[idx] = h;
    base[numel + idx] = bf16rne(x - bff(h));
}

typedef __attribute__((ext_vector_type(8))) short bf16x8;
typedef __attribute__((ext_vector_type(4))) float f32x4;

#define MF16(a, b, c) __builtin_amdgcn_mfma_f32_16x16x32_bf16((a), (b), (c), 0, 0, 0)

// ---------------------------------------------------------------- unified prep kernel
__global__ __launch_bounds__(256) void prep_kernel(
    const float* __restrict__ w0, const float* __restrict__ w1,
    const float* __restrict__ w2, const float* __restrict__ w3,
    const float* __restrict__ w4, const float* __restrict__ w5,
    const float* __restrict__ w6, const float* __restrict__ w8,
    const float* __restrict__ w9, const float* __restrict__ w10,
    const float* __restrict__ w11, const float* __restrict__ w12,
    const float* __restrict__ w13, const float* __restrict__ w14,
    const float* __restrict__ wf1, const float* __restrict__ bf1,
    const float* __restrict__ xyz,
    float* __restrict__ wt, float* __restrict__ gbuf, float* __restrict__ sqbuf,
    unsigned short* __restrict__ xyzp) {
    const int g = blockIdx.x * 256 + threadIdx.x;
    unsigned short* wus = (unsigned short*)(wt + 3840);

    if (g < 3584) {                              // e1 weights (fp32, [i][o])
        if (g < 320)       { int i = g >> 5, o = g & 31;             wt[g] = w0[o * 10 + i]; }
        else if (g < 1344) { int l = g - 320;  int i = l >> 5, o = l & 31; wt[g] = w1[o * 32 + i]; }
        else if (g < 1536) { int l = g - 1344; int i = l >> 5, o = l & 31; wt[g] = w2[o * 6 + i]; }
        else if (g < 2560) { int l = g - 1536; int i = l >> 5, o = l & 31; wt[g] = w3[o * 32 + i]; }
        else               { int l = g - 2560; int i = l >> 5, o = l & 31; wt[g] = w4[o * 32 + i]; }
    }
    else if (g < 3840)   { int l = g - 3584; wt[g] = (l < 128) ? bf1[l] : 0.0f; }                      // bpre
    else if (g < 12032)  { int l = g - 3840; int o = l >> 5, i = l & 31;                               // wpre 256x32
                           float x = (o < 128) ? wf1[o * 64 + i] : wf1[(o - 128) * 64 + 32 + i];
                           cvt_hl(wus + 0, 8192, l, x); }
    else if (g < 28416)  { int l = g - 12032;  cvt_hl(wus + 16384, 16384, l, w10[l]); }                // wc1 128x128
    else if (g < 159488) { int l = g - 28416;  cvt_hl(wus + 49152, 131072, l, w11[l]); }               // wc2 1024x128
    else if (g < 241408) { int l = g - 159488; int o = l / 160, i = l - o * 160;                       // wc3 512x160
                           cvt_hl(wus + 311296, 81920, l, w12[o * 1184 + i]); }
    else if (g < 372480) { int l = g - 241408; cvt_hl(wus + 475136, 131072, l, w13[l]); }              // wc4 256x512
    else if (g < 405248) { int l = g - 372480; cvt_hl(wus + 737280, 32768, l, w14[l]); }               // wc5 128x256
    else if (g < 409344) { int l = g - 405248; int o = l >> 5, k = l & 31;                             // wg1p 128x32 pad
                           float x = (k < 10) ? w5[o * 10 + k] : 0.0f;
                           cvt_hl(wus + 802816, 4096, l, x); }
    else if (g < 425728) { int l = g - 409344; cvt_hl(wus + 811008, 16384, l, w6[l]); }                // wg2p 128x128
    else if (g < 442112) { int l = g - 425728; cvt_hl(wus + 843776, 16384, l, w8[l]); }                // wf2p
    else if (g < 458496) { int l = g - 442112; cvt_hl(wus + 876544, 16384, l, w9[l]); }                // wf3p
    else if (g < 466688) { gbuf[g - 458496] = 0.0f; }
    else if (g < 499456) { int l = g - 466688;
                           const float* p = xyz + (size_t)l * 3;
                           sqbuf[l] = fmaf(p[0], p[0], fmaf(p[1], p[1], p[2] * p[2])); }
    else if (g < 532224) {                       // xyz h/m/l planes, K=32 zero-padded
        int row = g - 499456;
        const float* p = xyz + (size_t)row * 3;
        unsigned short hv[8] = {0,0,0,0,0,0,0,0};
        unsigned short mv[8] = {0,0,0,0,0,0,0,0};
        unsigned short lv[8] = {0,0,0,0,0,0,0,0};
        #pragma unroll
        for (int c = 0; c < 3; ++c) {
            float v = p[c];
            unsigned short h = bf16rne(v); float d = v - bff(h);
            unsigned short m = bf16rne(d);
            hv[c] = h; mv[c] = m; lv[c] = bf16rne(d - bff(m));
        }
        uint4 z = make_uint4(0u, 0u, 0u, 0u);
        unsigned short* d0 = xyzp + (size_t)row * 32;
        unsigned short* d1 = d0 + PL_;
        unsigned short* d2 = d0 + 2 * PL_;
        *(uint4*)d0 = *(uint4*)hv; *(uint4*)(d0 + 8) = z; *(uint4*)(d0 + 16) = z; *(uint4*)(d0 + 24) = z;
        *(uint4*)d1 = *(uint4*)mv; *(uint4*)(d1 + 8) = z; *(uint4*)(d1 + 16) = z; *(uint4*)(d1 + 24) = z;
        *(uint4*)d2 = *(uint4*)lv; *(uint4*)(d2 + 8) = z; *(uint4*)(d2 + 16) = z; *(uint4*)(d2 + 24) = z;
    }
}

// ---------------------------------------------------------------- fea1 -> h/m/l planes + sq (fused)
__global__ __launch_bounds__(256) void fea1p_kernel(
    const float* __restrict__ F, unsigned short* __restrict__ P, float* __restrict__ SQ) {
    int row = blockIdx.x * 256 + threadIdx.x;    // 32768 rows
    const float* x = F + (size_t)row * 32;
    float s = 0.0f;
    unsigned short hb[32], mb[32], lb[32];
    #pragma unroll
    for (int c = 0; c < 32; ++c) {
        float v = x[c];
        s = fmaf(v, v, s);
        unsigned short h = bf16rne(v); float d = v - bff(h);
        unsigned short m = bf16rne(d);
        hb[c] = h; mb[c] = m; lb[c] = bf16rne(d - bff(m));
    }
    SQ[row] = s;
    unsigned short* d0 = P + (size_t)row * 32;
    #pragma unroll
    for (int q = 0; q < 4; ++q) {
        *(uint4*)(d0 + 8 * q)           = *(uint4*)&hb[8 * q];
        *(uint4*)(d0 + PL_ + 8 * q)     = *(uint4*)&mb[8 * q];
        *(uint4*)(d0 + 2 * PL_ + 8 * q) = *(uint4*)&lb[8 * q];
    }
}

// ---------------------------------------------------------------- knn (top-16, MFMA two-pass)
// 128 rows / 8 waves per block (512 threads): B-panel staging + barriers amortized over
// 2x the rows vs the 64-row block; per-thread stream (row,quarter) math unchanged
// -> bit-identical output. LDS ~50KB -> 3 blocks/CU (24 waves/CU).

__device__ __forceinline__ void cas_asc(unsigned long long& x, unsigned long long& y) {
    unsigned long long a = x, b = y;
    bool sw = a > b;
    x = sw ? b : a;
    y = sw ? a : b;
}

__device__ __forceinline__ void merge_top(unsigned long long (&k)[16],
                                          const unsigned long long (&o)[16]) {
    #pragma unroll
    for (int i = 0; i < 16; ++i) {
        unsigned long long bb = o[15 - i];
        if (bb > k[i]) k[i] = bb;
    }
    #pragma unroll
    for (int st = 8; st >= 1; st >>= 1)
        #pragma unroll
        for (int i = 0; i < 16; ++i)
            if ((i & st) == 0) cas_asc(k[i], k[i + st]);
}

__device__ __forceinline__ void casv(float& x, float& y) {
    float lo = fminf(x, y), hi = fmaxf(x, y);
    x = lo; y = hi;
}

__device__ __forceinline__ void sortv16(float (&v)[16]) {   // ascending
    #pragma unroll
    for (int sz = 2; sz <= 16; sz <<= 1)
        #pragma unroll
        for (int st = sz >> 1; st >= 1; st >>= 1)
            #pragma unroll
            for (int i = 0; i < 16; ++i)
                if ((i & st) == 0) {
                    if ((i & sz) == 0) casv(v[i], v[i + st]);
                    else                casv(v[i + st], v[i]);
                }
}

__device__ __forceinline__ void mergev(float (&kv)[16], const float (&nv)[16]) {
    #pragma unroll
    for (int i = 0; i < 16; ++i) kv[i] = fmaxf(kv[i], nv[15 - i]);
    #pragma unroll
    for (int st = 8; st >= 1; st >>= 1)
        #pragma unroll
        for (int i = 0; i < 16; ++i)
            if ((i & st) == 0) casv(kv[i], kv[i + st]);
}

__global__ __launch_bounds__(512, 2) void knn_kernel(
    const unsigned short* __restrict__ P, const float* __restrict__ SQ,
    unsigned long long* __restrict__ Kout) {
    __shared__ __align__(16) unsigned short Bs[3][64][40];   // 15360 B
    __shared__ __align__(16) char U[34816];                  // Ds (pass1, per-wave) | cap (pass2)
    __shared__ float tau_sm[128];
    __shared__ int cnt[128];
    const int t = threadIdx.x;
    const int b = blockIdx.y;
    const int r0 = blockIdx.x * 128;
    const int half = blockIdx.z;
    const int H0 = half * 2048;
    const int lane = t & 63, w = t >> 6;                     // w in 0..7
    const int lr = lane & 15, lg = lane >> 4;
    const int kb = lg << 3;
    const int sc = t >> 3, sq2 = (t & 7) << 2;               // staging: col, 4-ush chunk

    float* Ds = (float*)U + w * 1088;                        // [16][68] per wave
    unsigned long long* cap = (unsigned long long*)U;        // [128][32] (pass2 overlay)

    const unsigned short* ap = P + ((size_t)(b * N_) + r0 + 16 * w + lr) * 32 + kb;
    const bf16x8 ah = *(const bf16x8*)ap;
    const bf16x8 am = *(const bf16x8*)(ap + PL_);
    const bf16x8 al = *(const bf16x8*)(ap + 2 * PL_);
    const f32x4 sqr4 = *(const f32x4*)&SQ[(size_t)b * N_ + r0 + 16 * w + 4 * lg];

    const float* SQc = SQ + (size_t)b * N_ + H0;
    const unsigned short* Pc = P + ((size_t)(b * N_) + H0) * 32;

    uint2 sgh, sgm, sgl;                                     // staging registers
    auto issue = [&](int tt) {
        const unsigned short* src = Pc + (size_t)(tt * 64 + sc) * 32 + sq2;
        sgh = *(const uint2*)src;
        sgm = *(const uint2*)(src + PL_);
        sgl = *(const uint2*)(src + 2 * PL_);
    };
    auto commit = [&]() {
        *(uint2*)&Bs[0][sc][sq2] = sgh;
        *(uint2*)&Bs[1][sc][sq2] = sgm;
        *(uint2*)&Bs[2][sc][sq2] = sgl;
    };

    float kv[16];
    #pragma unroll
    for (int j = 0; j < 16; ++j) kv[j] = -3.4e38f;

    issue(0);
    // ---- pass 1 ----
    for (int tt = 0; tt < 32; ++tt) {
        commit();
        __syncthreads();                                     // Bs ready
        if (tt + 1 < 32) issue(tt + 1);                      // latency hides under compute
        #pragma unroll
        for (int j = 0; j < 4; ++j) {
            int cc = 16 * j + lr;
            bf16x8 bh = *(const bf16x8*)&Bs[0][cc][kb];
            bf16x8 bm = *(const bf16x8*)&Bs[1][cc][kb];
            bf16x8 bl = *(const bf16x8*)&Bs[2][cc][kb];
            f32x4 a = {0.0f, 0.0f, 0.0f, 0.0f};
            a = MF16(ah, bh, a); a = MF16(am, bh, a); a = MF16(ah, bm, a);
            a = MF16(am, bm, a); a = MF16(al, bh, a); a = MF16(ah, bl, a);
            float sqcv = SQc[tt * 64 + cc];
            #pragma unroll
            for (int r = 0; r < 4; ++r)
                Ds[(4 * lg + r) * 68 + cc] = fmaf(2.0f, a[r], -sqr4[r]) - sqcv;
        }
        float nv[16];
        #pragma unroll
        for (int q = 0; q < 4; ++q)
            *(float4*)&nv[4 * q] = *(const float4*)&Ds[lr * 68 + lg * 16 + 4 * q];
        sortv16(nv);
        mergev(kv, nv);
        __syncthreads();                                     // Bs reads done
    }
    issue(0);                                                // pass-2 tile 0 prefetch

    // ---- tau: merge 4 quarters across lanes (shfl), 16th value per row ----
    #pragma unroll
    for (int st = 16; st <= 32; st <<= 1) {
        float ov[16];
        #pragma unroll
        for (int i = 0; i < 16; ++i) ov[i] = __shfl_xor(kv[15 - i], st);
        #pragma unroll
        for (int i = 0; i < 16; ++i) kv[i] = fmaxf(kv[i], ov[i]);
        #pragma unroll
        for (int s2 = 8; s2 >= 1; s2 >>= 1)
            #pragma unroll
            for (int i = 0; i < 16; ++i)
                if ((i & s2) == 0) casv(kv[i], kv[i + s2]);
    }
    if (lane < 16) { tau_sm[w * 16 + lane] = kv[0]; cnt[w * 16 + lane] = 0; }
    const f32x4 taur4 = *(const f32x4*)&tau_sm[w * 16 + 4 * lg];   // wave-local, lgkm-ordered

    // ---- pass 2: recompute, compact e >= tau ----
    for (int tt = 0; tt < 32; ++tt) {
        commit();
        __syncthreads();                                     // also guards Ds->cap overlay
        if (tt + 1 < 32) issue(tt + 1);
        #pragma unroll
        for (int j = 0; j < 4; ++j) {
            int cc = 16 * j + lr;
            bf16x8 bh = *(const bf16x8*)&Bs[0][cc][kb];
            bf16x8 bm = *(const bf16x8*)&Bs[1][cc][kb];
            bf16x8 bl = *(const bf16x8*)&Bs[2][cc][kb];
            f32x4 a = {0.0f, 0.0f, 0.0f, 0.0f};
            a = MF16(ah, bh, a); a = MF16(am, bh, a); a = MF16(ah, bm, a);
            a = MF16(am, bm, a); a = MF16(al, bh, a); a = MF16(ah, bl, a);
            float sqcv = SQc[tt * 64 + cc];
            #pragma unroll
            for (int r = 0; r < 4; ++r) {
                float e = fmaf(2.0f, a[r], -sqr4[r]) - sqcv;
                if (e >= taur4[r]) {
                    int row = 16 * w + 4 * lg + r;
                    unsigned int u = __float_as_uint(e);
                    unsigned int ou = (u & 0x80000000u) ? ~u : (u | 0x80000000u);
                    unsigned long long key = ((unsigned long long)ou << 32)
                                           | (unsigned int)(4095 - (H0 + tt * 64 + cc));
                    int pos = atomicAdd(&cnt[row], 1);
                    if (pos < 32) cap[row * 32 + pos] = key;
                }
            }
        }
        __syncthreads();
    }

    // ---- final per-row exact top-16 (u64 keys, asc) ----
    if (t < 128) {
        int n = min(cnt[t], 32);
        unsigned long long K[16];
        #pragma unroll
        for (int j = 0; j < 16; ++j) K[j] = 0ull;
        for (int i = 0; i < n; ++i) {
            unsigned long long v = cap[t * 32 + i];
            if (v > K[0]) {
                K[0] = v;
                #pragma unroll
                for (int s = 0; s < 15; ++s) cas_asc(K[s], K[s + 1]);
            }
        }
        size_t obase = (((size_t)b * 2 + half) * N_ + r0 + t) * 16;
        #pragma unroll
        for (int j = 0; j < 16; ++j) Kout[obase + j] = K[j];
    }
}

__global__ __launch_bounds__(256) void knn_merge_kernel(
    const unsigned long long* __restrict__ Kbuf, int* __restrict__ IDX) {
    int gid = blockIdx.x * 256 + threadIdx.x;
    int b = gid >> 12, r = gid & 4095;
    unsigned long long K0[16], K1[16];
    const unsigned long long* p0 = Kbuf + (((size_t)b * 2 + 0) * N_ + r) * 16;
    const unsigned long long* p1 = Kbuf + (((size_t)b * 2 + 1) * N_ + r) * 16;
    #pragma unroll
    for (int j = 0; j < 16; ++j) { K0[j] = p0[j]; K1[j] = p1[j]; }
    merge_top(K0, K1);
    size_t ob = ((size_t)b * N_ + r) * 16;
    #pragma unroll
    for (int j = 0; j < 16; ++j)
        IDX[ob + j] = 4095 - (int)(unsigned int)(K0[15 - j] & 0xFFFFFFFFu);
}

// ---------------------------------------------------------------- edgeconv 1 (xyz, C=3 -> 32)

__global__ __launch_bounds__(256, 4) void e1_kernel(
    const float* __restrict__ xyz, const int* __restrict__ idx1,
    const float* __restrict__ wte1,
    const float* __restrict__ bg1, const float* __restrict__ bg2,
    const float* __restrict__ bf1, const float* __restrict__ bf2,
    const float* __restrict__ bf3,
    float* __restrict__ fea1) {
    __shared__ __align__(16) float Ain[10 * 132];
    __shared__ __align__(16) float Bu0[32 * 132];
    __shared__ __align__(16) float Bu1[32 * 132];
    __shared__ __align__(16) float wl[3584];
    __shared__ float bl[5][32];
    __shared__ __align__(16) float Pm1[4][8][32];
    __shared__ int idxl[128];
    const int t = threadIdx.x;
    const int b = blockIdx.x >> 9;
    const int n0 = (blockIdx.x & 511) << 3;
    const int et = (t & 31) << 2;
    const int ct = (t >> 5) << 2;

    for (int i = t; i < 3584; i += 256) wl[i] = wte1[i];
    if (t < 32) {
        bl[0][t] = bg1[t]; bl[1][t] = bg2[t]; bl[2][t] = bf1[t];
        bl[3][t] = bf2[t]; bl[4][t] = bf3[t];
    }
    if (t < 128) idxl[t] = idx1[((size_t)b * N_ + n0 + (t >> 4)) * 16 + (t & 15)];
    __syncthreads();
    if (t < 128) {
        int p = t >> 4, n = n0 + p, m = idxl[t];
        const float* xc = xyz + ((size_t)b * N_ + n) * 3;
        const float* xk = xyz + ((size_t)b * N_ + m) * 3;
        float c0 = xc[0], c1v = xc[1], c2v = xc[2];
        float k0 = xk[0], k1 = xk[1], k2 = xk[2];
        float r0 = c0 - k0, r1 = c1v - k1, r2 = c2v - k2;
        Ain[0 * 132 + t] = sqrtf(r0 * r0 + r1 * r1 + r2 * r2);
        Ain[1 * 132 + t] = c0;  Ain[2 * 132 + t] = c1v; Ain[3 * 132 + t] = c2v;
        Ain[4 * 132 + t] = k0;  Ain[5 * 132 + t] = k1;  Ain[6 * 132 + t] = k2;
        Ain[7 * 132 + t] = r0;  Ain[8 * 132 + t] = r1;  Ain[9 * 132 + t] = r2;
    }
    __syncthreads();

    float acc[4][4];
    auto gem = [&](int KK, const float* Asrc, int woff) {
        #pragma unroll
        for (int ii = 0; ii < 4; ++ii)
            #pragma unroll
            for (int jj = 0; jj < 4; ++jj) acc[ii][jj] = 0.0f;
        for (int i = 0; i < KK; ++i) {
            float a4[4], w4[4];
            *(float4*)a4 = *(const float4*)&Asrc[i * 132 + et];
            *(float4*)w4 = *(const float4*)&wl[woff + i * 32 + ct];
            #pragma unroll
            for (int ii = 0; ii < 4; ++ii)
                #pragma unroll
                for (int jj = 0; jj < 4; ++jj)
                    acc[ii][jj] = fmaf(a4[ii], w4[jj], acc[ii][jj]);
        }
    };
    auto wrout = [&](float* dst, const float* brow) {
        #pragma unroll
        for (int jj = 0; jj < 4; ++jj) {
            float tmp[4];
            #pragma unroll
            for (int ii = 0; ii < 4; ++ii) tmp[ii] = fmaxf(acc[ii][jj] + brow[ct + jj], 0.0f);
            *(float4*)&dst[(ct + jj) * 132 + et] = *(float4*)tmp;
        }
    };

    gem(10, Ain, 0);          wrout(Bu1, bl[0]);   __syncthreads();
    gem(32, Bu1, 320);
    float g2r[4][4];
    #pragma unroll
    for (int ii = 0; ii < 4; ++ii)
        #pragma unroll
        for (int jj = 0; jj < 4; ++jj)
            g2r[ii][jj] = fmaxf(acc[ii][jj] + bl[1][ct + jj], 0.0f);
    gem(6, Ain + 132, 1344);  wrout(Bu0, bl[2]);   __syncthreads();
    gem(32, Bu0, 1536);       wrout(Bu1, bl[3]);   __syncthreads();
    gem(32, Bu1, 2560);

    float pm[4];
    #pragma unroll
    for (int jj = 0; jj < 4; ++jj) {
        float mx = 0.0f;
        #pragma unroll
        for (int ii = 0; ii < 4; ++ii) {
            float f3 = fmaxf(acc[ii][jj] + bl[4][ct + jj], 0.0f);
            mx = fmaxf(mx, g2r[ii][jj] * f3);
        }
        pm[jj] = mx;
    }
    const int sub = t & 3, pl = (t & 31) >> 2;
    *(float4*)&Pm1[sub][pl][ct] = *(float4*)pm;
    __syncthreads();
    {
        int p = t >> 5, c = t & 31;
        float v = fmaxf(fmaxf(Pm1[0][p][c], Pm1[1][p][c]), fmaxf(Pm1[2][p][c], Pm1[3][p][c]));
        fea1[((size_t)b * N_ + n0 + p) * 32 + c] = v;
    }
}

// ---------------------------------------------------------------- edgeconv 2 (split-bf16 MFMA, o-quarter waves)
// 8 points / 128 edges per block, 256 threads, 4 waves. Wave w owns o-quarter
// [32w, 32w+32) x ALL 128 edges (W panels disjoint across waves -> minimal W traffic).
// Measured R9: 268us, MfmaUtil 27.4%. Bit-identical MFMA sequence per accumulator.

__global__ __launch_bounds__(256, 2) void e2_kernel(
    const float* __restrict__ xyz, const int* __restrict__ idx2,
    const float* __restrict__ CfPf,
    const unsigned short* __restrict__ wg1p, const unsigned short* __restrict__ wg2p,
    const unsigned short* __restrict__ wf2p, const unsigned short* __restrict__ wf3p,
    const float* __restrict__ bg1, const float* __restrict__ bg2,
    const float* __restrict__ bf2, const float* __restrict__ bf3,
    float* __restrict__ fea2) {
    __shared__ __align__(16) unsigned short Ah[128 * 128];   // 32KB hi plane [e][ch]
    __shared__ __align__(16) unsigned short Al[128 * 128];   // 32KB lo plane
    __shared__ float bb[4][128];
    __shared__ int idxl[128];
    const int t = threadIdx.x;
    const int b = blockIdx.x >> 9;
    const int n0 = (blockIdx.x & 511) << 3;
    const int lane = t & 63, w = t >> 6;
    const int wr = w << 5;           // o quarter: 0/32/64/96
    const int lr = lane & 15, lg = lane >> 4;
    const int kb = lg << 3;

    auto swz = [](int e, int bo) { return e * 256 + (bo ^ ((e & 7) << 4)); };

    for (int i = t; i < 512; i += 256) {
        const float* bp = (i < 128) ? bg1 : (i < 256) ? bg2 : (i < 384) ? bf2 : bf3;
        bb[i >> 7][i & 127] = bp[i & 127];
    }
    if (t < 128) idxl[t] = idx2[((size_t)b * N_ + n0 + (t >> 4)) * 16 + (t & 15)];
    __syncthreads();

    f32x4 acc[2][8];
    const f32x4 zz = {0.0f, 0.0f, 0.0f, 0.0f};
    auto zacc = [&]() {
        #pragma unroll
        for (int i = 0; i < 2; ++i)
            #pragma unroll
            for (int j = 0; j < 8; ++j) acc[i][j] = zz;
    };

    {   // ---- g1: per-j geometry B-fragment in registers, K=32 (10 real + 22 zero) ----
        zacc();
        bf16x8 wh[2], wl_[2];
        #pragma unroll
        for (int i = 0; i < 2; ++i) {
            size_t off = (size_t)(wr + i * 16 + lr) * 32 + kb;
            wh[i] = *(const bf16x8*)(wg1p + off);
            wl_[i] = *(const bf16x8*)(wg1p + 4096 + off);
        }
        #pragma unroll
        for (int j = 0; j < 8; ++j) {
            float gv[8];
            #pragma unroll
            for (int q = 0; q < 8; ++q) gv[q] = 0.0f;
            if (lg < 2) {
                int e = j * 16 + lr;
                int p = e >> 4, m = idxl[e];
                const float* xc = xyz + ((size_t)b * N_ + n0 + p) * 3;
                const float* xk = xyz + ((size_t)b * N_ + m) * 3;
                float c0 = xc[0], c1 = xc[1], c2 = xc[2];
                float k0 = xk[0], k1 = xk[1], k2 = xk[2];
                float r0 = c0 - k0, r1 = c1 - k1, r2 = c2 - k2;
                if (lg == 0) {
                    gv[0] = sqrtf(r0 * r0 + r1 * r1 + r2 * r2);
                    gv[1] = c0; gv[2] = c1; gv[3] = c2;
                    gv[4] = k0; gv[5] = k1; gv[6] = k2; gv[7] = r0;
                } else { gv[0] = r1; gv[1] = r2; }
            }
            bf16x8 gbh, gbl;
            #pragma unroll
            for (int q = 0; q < 8; ++q) {
                unsigned short h = bf16rne(gv[q]);
                gbh[q] = (short)h;
                gbl[q] = (short)bf16rne(gv[q] - bff(h));
            }
            #pragma unroll
            for (int i = 0; i < 2; ++i) {
                acc[i][j] = MF16(wh[i], gbh, acc[i][j]);
                acc[i][j] = MF16(wl_[i], gbh, acc[i][j]);
                acc[i][j] = MF16(wh[i], gbl, acc[i][j]);
            }
        }
    }

    auto epi_store = [&](const float* brow) {
        #pragma unroll
        for (int i = 0; i < 2; ++i) {
            int o4 = wr + i * 16 + lg * 4;
            float bv[4];
            *(float4*)bv = *(const float4*)&brow[o4];
            #pragma unroll
            for (int j = 0; j < 8; ++j) {
                int e = j * 16 + lr;
                unsigned short h[4], l[4];
                #pragma unroll
                for (int r = 0; r < 4; ++r) {
                    float v = fmaxf(acc[i][j][r] + bv[r], 0.0f);
                    h[r] = bf16rne(v);
                    l[r] = bf16rne(v - bff(h[r]));
                }
                int bo = swz(e, o4 * 2);
                *(ushort4*)((char*)Ah + bo) = make_ushort4(h[0], h[1], h[2], h[3]);
                *(ushort4*)((char*)Al + bo) = make_ushort4(l[0], l[1], l[2], l[3]);
            }
        }
    };
    epi_store(bb[0]);
    __syncthreads();

    auto gemmK = [&](const unsigned short* __restrict__ Wp) {
        zacc();
        #pragma unroll
        for (int ks = 0; ks < 4; ++ks) {
            bf16x8 wh[2], wl_[2];
            #pragma unroll
            for (int i = 0; i < 2; ++i) {
                size_t off = (size_t)(wr + i * 16 + lr) * 128 + ks * 32 + kb;
                wh[i] = *(const bf16x8*)(Wp + off);
                wl_[i] = *(const bf16x8*)(Wp + 16384 + off);
            }
            #pragma unroll
            for (int jh = 0; jh < 2; ++jh) {
                bf16x8 xh[4], xl[4];
                #pragma unroll
                for (int jj = 0; jj < 4; ++jj) {
                    int e = (jh * 4 + jj) * 16 + lr;
                    int bo = swz(e, (ks * 32 + kb) * 2);
                    xh[jj] = *(const bf16x8*)((const char*)Ah + bo);
                    xl[jj] = *(const bf16x8*)((const char*)Al + bo);
                }
                #pragma unroll
                for (int i = 0; i < 2; ++i) {
                    #pragma unroll
                    for (int jj = 0; jj < 4; ++jj) {
                        int j = jh * 4 + jj;
                        acc[i][j] = MF16(wh[i], xh[jj], acc[i][j]);
                        acc[i][j] = MF16(wl_[i], xh[jj], acc[i][j]);
                        acc[i][j] = MF16(wh[i], xl[jj], acc[i][j]);
                    }
                }
            }
        }
    };

    gemmK(wg2p);
    float g2r[2][8][4];
    #pragma unroll
    for (int i = 0; i < 2; ++i) {
        float bv[4];
        *(float4*)bv = *(const float4*)&bb[1][wr + i * 16 + lg * 4];
        #pragma unroll
        for (int j = 0; j < 8; ++j)
            #pragma unroll
            for (int r = 0; r < 4; ++r)
                g2r[i][j][r] = fmaxf(acc[i][j][r] + bv[r], 0.0f);
    }
    __syncthreads();

    {   // ---- f1: gather relu(Cf[n] + Pf[m]) -> planes ----
        int e = t & 127, hf = t >> 7;
        int n = n0 + (e >> 4), m = idxl[e];
        const float* crow = CfPf + ((size_t)b * N_ + n) * 256 + hf * 64;
        const float* prow = CfPf + ((size_t)b * N_ + m) * 256 + 128 + hf * 64;
        #pragma unroll
        for (int q = 0; q < 16; ++q) {
            float4 cc = *(const float4*)(crow + q * 4);
            float4 pp = *(const float4*)(prow + q * 4);
            float v[4] = { fmaxf(cc.x + pp.x, 0.0f), fmaxf(cc.y + pp.y, 0.0f),
                           fmaxf(cc.z + pp.z, 0.0f), fmaxf(cc.w + pp.w, 0.0f) };
            unsigned short h[4], l[4];
            #pragma unroll
            for (int r = 0; r < 4; ++r) {
                h[r] = bf16rne(v[r]);
                l[r] = bf16rne(v[r] - bff(h[r]));
            }
            int bo = swz(e, (hf * 64 + q * 4) * 2);
            *(ushort4*)((char*)Ah + bo) = make_ushort4(h[0], h[1], h[2], h[3]);
            *(ushort4*)((char*)Al + bo) = make_ushort4(l[0], l[1], l[2], l[3]);
        }
    }
    __syncthreads();

    gemmK(wf2p);
    __syncthreads();
    epi_store(bb[2]);
    __syncthreads();

    gemmK(wf3p);
    #pragma unroll
    for (int j = 0; j < 8; ++j) {
        int p = j;                       // point within block (0..7)
        #pragma unroll
        for (int i = 0; i < 2; ++i) {
            int o4 = wr + i * 16 + lg * 4;
            float bv[4];
            *(float4*)bv = *(const float4*)&bb[3][o4];
            float vr[4];
            #pragma unroll
            for (int r = 0; r < 4; ++r) {
                float f3v = fmaxf(acc[i][j][r] + bv[r], 0.0f);
                float v = g2r[i][j][r] * f3v;
                v = fmaxf(v, __shfl_xor(v, 1));
                v = fmaxf(v, __shfl_xor(v, 2));
                v = fmaxf(v, __shfl_xor(v, 4));
                v = fmaxf(v, __shfl_xor(v, 8));
                vr[r] = v;
            }
            if (lr == 0)
                *(float4*)(fea2 + ((size_t)b * N_ + n0 + p) * 128 + o4) = *(float4*)vr;
        }
    }
}

// ---------------------------------------------------------------- split-bf16 MFMA pointwise GEMM (head)

template<int RELU, int BMODE, int GMAX>
__global__ __launch_bounds__(256) void gemm_mfma(
    const float* __restrict__ X1, int S1, int K1,
    const float* __restrict__ X2, int S2, int Ktot,
    const unsigned short* __restrict__ Wc, const float* __restrict__ bias,
    float* __restrict__ Y, int COUT, float* __restrict__ gout) {
    __shared__ __align__(16) unsigned short Xh[128 * 40];
    __shared__ __align__(16) unsigned short Xl[128 * 40];
    __shared__ __align__(16) unsigned short Wh[128 * 40];
    __shared__ __align__(16) unsigned short Wl[128 * 40];
    __shared__ float Gm[2][128];
    const int t = threadIdx.x;
    const int m0 = blockIdx.x * 128, o0 = blockIdx.y * 128;
    const int lane = t & 63, w = t >> 6;
    const int wr = (w >> 1) << 6, wc = (w & 1) << 6;
    const int lr = lane & 15, lg = lane >> 4;
    const int kb = lg << 3;
    const size_t WN = (size_t)COUT * Ktot;

    f32x4 acc[4][4];
    const f32x4 zz = {0.0f, 0.0f, 0.0f, 0.0f};
    #pragma unroll
    for (int i = 0; i < 4; ++i)
        #pragma unroll
        for (int j = 0; j < 4; ++j) acc[i][j] = zz;

    const int ntile = Ktot >> 5;
    for (int kt = 0; kt < ntile; ++kt) {
        const int kbase = kt << 5;
        const float* Xp; int S, koff;
        if (kbase < K1) { Xp = X1; S = S1; koff = kbase; }
        else            { Xp = X2; S = S2; koff = kbase - K1; }
        #pragma unroll
        for (int rr = 0; rr < 4; ++rr) {
            int idx = t + rr * 256;
            int p = idx >> 3, i4 = (idx & 7) << 2;
            const float4 v = *(const float4*)(Xp + (size_t)(m0 + p) * S + koff + i4);
            unsigned short h0 = bf16rne(v.x), h1 = bf16rne(v.y);
            unsigned short h2 = bf16rne(v.z), h3 = bf16rne(v.w);
            *(ushort4*)&Xh[p * 40 + i4] = make_ushort4(h0, h1, h2, h3);
            *(ushort4*)&Xl[p * 40 + i4] = make_ushort4(
                bf16rne(v.x - bff(h0)), bf16rne(v.y - bff(h1)),
                bf16rne(v.z - bff(h2)), bf16rne(v.w - bff(h3)));
        }
        #pragma unroll
        for (int rr = 0; rr < 2; ++rr) {
            int c = t + rr * 256;
            int o = c >> 2, k8 = (c & 3) << 3;
            const unsigned short* src = Wc + (size_t)(o0 + o) * Ktot + kbase + k8;
            *(uint4*)&Wh[o * 40 + k8] = *(const uint4*)src;
            *(uint4*)&Wl[o * 40 + k8] = *(const uint4*)(src + WN);
        }
        __syncthreads();

        bf16x8 ah[4], al[4], bh[4], bl[4];
        #pragma unroll
        for (int f = 0; f < 4; ++f) {
            ah[f] = *(const bf16x8*)&Xh[(wr + f * 16 + lr) * 40 + kb];
            al[f] = *(const bf16x8*)&Xl[(wr + f * 16 + lr) * 40 + kb];
            bh[f] = *(const bf16x8*)&Wh[(wc + f * 16 + lr) * 40 + kb];
            bl[f] = *(const bf16x8*)&Wl[(wc + f * 16 + lr) * 40 + kb];
        }
        #pragma unroll
        for (int i = 0; i < 4; ++i)
            #pragma unroll
            for (int j = 0; j < 4; ++j) {
                acc[i][j] = MF16(ah[i], bh[j], acc[i][j]);
                acc[i][j] = MF16(al[i], bh[j], acc[i][j]);
                acc[i][j] = MF16(ah[i], bl[j], acc[i][j]);
            }
        __syncthreads();
    }

    const int b = m0 >> 12;
    if (GMAX) {
        #pragma unroll
        for (int j = 0; j < 4; ++j) {
            const int oc = wc + j * 16 + lr;
            const float bv = bias[o0 + oc];
            float mx = 0.0f;
            #pragma unroll
            for (int i = 0; i < 4; ++i)
                #pragma unroll
                for (int r = 0; r < 4; ++r) {
                    float v = acc[i][j][r] + bv;
                    if (RELU) v = fmaxf(v, 0.0f);
                    mx = fmaxf(mx, v);
                }
            mx = fmaxf(mx, __shfl_xor(mx, 16));
            mx = fmaxf(mx, __shfl_xor(mx, 32));
            if (lane < 16) Gm[w >> 1][wc + j * 16 + lane] = mx;
        }
        __syncthreads();
        if (t < 128) {
            float v = fmaxf(Gm[0][t], Gm[1][t]);
            atomicMax((unsigned int*)(gout + b * 1024 + o0 + t), __float_as_uint(v));
        }
    } else {
        #pragma unroll
        for (int j = 0; j < 4; ++j) {
            const int oc = wc + j * 16 + lr;
            const float bv = (BMODE == 0) ? bias[o0 + oc] : bias[b * 512 + o0 + oc];
            #pragma unroll
            for (int i = 0; i < 4; ++i) {
                float* yp = Y + (size_t)(m0 + wr + i * 16 + lg * 4) * COUT + o0 + oc;
                #pragma unroll
                for (int r = 0; r < 4; ++r) {
                    float v = acc[i][j][r] + bv;
                    if (RELU) v = fmaxf(v, 0.0f);
                    yp[(size_t)r * COUT] = v;
                }
            }
        }
    }
}

// ---------------------------------------------------------------- bias3 = W_c3[:,160:] @ g + b_c3

__global__ void bias3_kernel(const float* __restrict__ g, const float* __restrict__ w_c3,
                             const float* __restrict__ b_c3, float* __restrict__ bias3) {
    __shared__ float gs[1024];
    int b = blockIdx.x >> 1;
    int o = ((blockIdx.x & 1) << 8) + threadIdx.x;
    for (int i = threadIdx.x; i < 1024; i += 256) gs[i] = g[b * 1024 + i];
    __syncthreads();
    float acc = b_c3[o];
    const float* wr = w_c3 + (size_t)o * 1184 + 160;
    for (int i = 0; i < 1024; i += 4) {
        float4 w4 = *(const float4*)(wr + i);
        acc = fmaf(w4.x, gs[i], acc);     acc = fmaf(w4.y, gs[i + 1], acc);
        acc = fmaf(w4.z, gs[i + 2], acc); acc = fmaf(w4.w, gs[i + 3], acc);
    }
    bias3[b * 512 + o] = acc;
}

// ---------------------------------------------------------------- final 128 -> 13 (no relu), output (B,13,N)

__global__ __launch_bounds__(256, 1) void c6_kernel(
    const float* __restrict__ h5, const float* __restrict__ w,
    const float* __restrict__ bias, float* __restrict__ out) {
    __shared__ float ws[13 * 128];
    __shared__ float bs[13];
    int t = threadIdx.x;
    for (int i = t; i < 13 * 128; i += 256) ws[i] = w[i];
    if (t < 13) bs[t] = bias[t];
    __syncthreads();
    int b = blockIdx.x >> 4;
    int n = ((blockIdx.x & 15) << 8) + t;
    float x[128];
    const float* xp = h5 + ((size_t)b * N_ + n) * 128;
    #pragma unroll
    for (int i = 0; i < 128; i += 4) *(float4*)&x[i] = *(const float4*)(xp + i);
    for (int o = 0; o < 13; ++o) {
        float acc = bs[o];
        #pragma unroll
        for (int i = 0; i < 128; ++i) acc = fmaf(ws[o * 128 + i], x[i], acc);
        out[((size_t)b * 13 + o) * N_ + n] = acc;
    }
}

// ---------------------------------------------------------------- launch

extern "C" void kernel_launch(void* const* d_in, const int* in_sizes, int n_in,
                              void* d_out, int out_size, void* d_ws, size_t ws_size,
                              hipStream_t stream) {
    (void)in_sizes; (void)n_in; (void)out_size; (void)ws_size;
    const float* xyz = (const float*)d_in[0];
    #define W_(j)  ((const float*)d_in[1 + 2 * (j)])
    #define Bp_(j) ((const float*)d_in[2 + 2 * (j)])

    char* ws = (char*)d_ws;
    const size_t MB = 1u << 20;
    int*   idx1  = (int*)(ws + 0 * MB);
    int*   idx2  = (int*)(ws + 2 * MB);
    float* fea1  = (float*)(ws + 4 * MB);
    float* CfPf  = (float*)(ws + 8 * MB);       // 32MB; overlays xyzp/feap planes; later h4
    float* fea2  = (float*)(ws + 40 * MB);
    float* h1    = (float*)(ws + 56 * MB);      // 16MB; reused later as h5
    float* sqbuf = (float*)(ws + 72 * MB);
    float* gbuf  = (float*)(ws + 72 * MB + (128u << 10));
    float* b3buf = (float*)(ws + 72 * MB + (160u << 10));
    float* wt    = (float*)(ws + 72 * MB + (176u << 10));
    float* h3    = (float*)(ws + 75 * MB);      // 64MB (also overlays knn Kbuf early)
    float* h4    = CfPf;
    float* h5    = h1;
    float* outp  = (float*)d_out;
    unsigned long long* Kbuf = (unsigned long long*)(ws + 75 * MB);
    unsigned short* xyzp = (unsigned short*)(ws + 8 * MB);    // 6MB, dead before CfPf written
    unsigned short* feap = (unsigned short*)(ws + 14 * MB);   // 6MB, dead before CfPf written

    // fp32 e1 weights + pre bias
    float* wte1  = wt;            // 3584
    float* bpre  = wt + 3584;     // 256
    // bf16 hi/lo planes ([o][k], lo at +numel)
    const unsigned short* wus = (const unsigned short*)(wt + 3840);
    const unsigned short* wpre = wus + 0;        // 256x32
    const unsigned short* wc1  = wus + 16384;    // 128x128
    const unsigned short* wc2  = wus + 49152;    // 1024x128
    const unsigned short* wc3  = wus + 311296;   // 512x160
    const unsigned short* wc4  = wus + 475136;   // 256x512
    const unsigned short* wc5  = wus + 737280;   // 128x256
    const unsigned short* wg1p = wus + 802816;   // 128x32 (padded)
    const unsigned short* wg2p = wus + 811008;   // 128x128
    const unsigned short* wf2p = wus + 843776;   // 128x128
    const unsigned short* wf3p = wus + 876544;   // 128x128

    prep_kernel<<<2079, 256, 0, stream>>>(
        W_(0), W_(1), W_(2), W_(3), W_(4), W_(5), W_(6), W_(8), W_(9), W_(10),
        W_(11), W_(12), W_(13), W_(14), W_(7), Bp_(7), xyz, wt, gbuf, sqbuf, xyzp);

    // knn1 + edgeconv1
    knn_kernel<<<dim3(32, 8, 2), 512, 0, stream>>>(xyzp, sqbuf, Kbuf);
    knn_merge_kernel<<<128, 256, 0, stream>>>(Kbuf, idx1);
    e1_kernel<<<4096, 256, 0, stream>>>(xyz, idx1, wte1, Bp_(0), Bp_(1), Bp_(2), Bp_(3), Bp_(4), fea1);

    // knn2 + edgeconv2
    fea1p_kernel<<<128, 256, 0, stream>>>(fea1, feap, sqbuf);
    knn_kernel<<<dim3(32, 8, 2), 512, 0, stream>>>(feap, sqbuf, Kbuf);
    knn_merge_kernel<<<128, 256, 0, stream>>>(Kbuf, idx2);
    gemm_mfma<0, 0, 0><<<dim3(256, 2), 256, 0, stream>>>(fea1, 32, 32, nullptr, 0, 32,
                                                         wpre, bpre, CfPf, 256, nullptr);
    e2_kernel<<<4096, 256, 0, stream>>>(xyz, idx2, CfPf, wg1p, wg2p, wf2p, wf3p,
                                        Bp_(5), Bp_(6), Bp_(8), Bp_(9), fea2);

    // head (split-bf16 MFMA)
    gemm_mfma<1, 0, 0><<<dim3(256, 1), 256, 0, stream>>>(fea2, 128, 128, nullptr, 0, 128,
                                                         wc1, Bp_(10), h1, 128, nullptr);
    gemm_mfma<1, 0, 1><<<dim3(256, 8), 256, 0, stream>>>(h1, 128, 128, nullptr, 0, 128,
                                                         wc2, Bp_(11), nullptr, 1024, gbuf);
    bias3_kernel<<<16, 256, 0, stream>>>(gbuf, W_(12), Bp_(12), b3buf);
    gemm_mfma<1, 1, 0><<<dim3(256, 4), 256, 0, stream>>>(fea1, 32, 32, fea2, 128, 160,
                                                         wc3, b3buf, h3, 512, nullptr);
    gemm_mfma<1, 0, 0><<<dim3(256, 2), 256, 0, stream>>>(h3, 512, 512, nullptr, 0, 512,
                                                         wc4, Bp_(13), h4, 256, nullptr);
    gemm_mfma<1, 0, 0><<<dim3(256, 1), 256, 0, stream>>>(h4, 256, 256, nullptr, 0, 256,
                                                         wc5, Bp_(14), h5, 128, nullptr);
    c6_kernel<<<128, 256, 0, stream>>>(h5, W_(15), Bp_(15), outp);
    #undef W_
    #undef Bp_
}